// Round 1
// baseline (1503.264 us; speedup 1.0000x reference)
//
#include <hip/hip_runtime.h>

// SA_Layer offset-attention, fp32, MI355X.
// B=16, C=256, N=2048.
// ws layout (floats): y[16*256*2048] | v[16*256*2048] | rsum[16*2048]  (~64.1 MB)

#define BB 16
#define CC 256
#define NN 2048

typedef float f4 __attribute__((ext_vector_type(4)));

#define SQRT_LOG2E 1.2011224087864498f  // sqrt(log2(e)); y scaled so e' = log2(e)*e
#define SHIFT 128.0f                    // constant softmax shift (safe: e' <= ~170)

// ---------------- K1: projection  Out[b][o][n] = scale * sum_c W[o][c] X[b][c][n] + bias[o]
// grid (NN/64, CC/128, BB), block 256
__global__ __launch_bounds__(256)
void proj_kernel(const float* __restrict__ X, const float* __restrict__ W,
                 const float* __restrict__ bias, float* __restrict__ Out, float scale)
{
    __shared__ float Wt[32][132];   // [k][o], o-tile 128
    __shared__ float Xs[32][68];    // [k][n], n-tile 64
    const int tid = threadIdx.x;
    const int bn0 = blockIdx.x * 64;
    const int bo0 = blockIdx.y * 128;
    const int b   = blockIdx.z;
    const int to = tid & 15;   // o = 4*to+i and 64+4*to+i
    const int tn = tid >> 4;   // n = 4*tn+j
    const float* Xb = X + (size_t)b * CC * NN;

    float acc[8][4];
#pragma unroll
    for (int i = 0; i < 8; ++i)
#pragma unroll
        for (int j = 0; j < 4; ++j) acc[i][j] = 0.f;

    for (int c0 = 0; c0 < CC; c0 += 32) {
        // stage W tile transposed: Wt[k][o] = W[bo0+o][c0+k]
        {
            const int o_l = tid >> 1;
            const int cb  = (tid & 1) * 16;
            const float* src = W + (size_t)(bo0 + o_l) * CC + c0 + cb;
            f4 w0 = *(const f4*)(src + 0);
            f4 w1 = *(const f4*)(src + 4);
            f4 w2 = *(const f4*)(src + 8);
            f4 w3 = *(const f4*)(src + 12);
#pragma unroll
            for (int q = 0; q < 4; ++q) {
                Wt[cb + q][o_l]      = w0[q];
                Wt[cb + 4 + q][o_l]  = w1[q];
                Wt[cb + 8 + q][o_l]  = w2[q];
                Wt[cb + 12 + q][o_l] = w3[q];
            }
        }
        // stage X tile: Xs[k][n] = X[b][c0+k][bn0+n]
        {
            const int idx = tid * 8;
            const int k   = idx >> 6;
            const int nn2 = idx & 63;
            const float* src = Xb + (size_t)(c0 + k) * NN + bn0 + nn2;
            *(f4*)&Xs[k][nn2]     = *(const f4*)(src);
            *(f4*)&Xs[k][nn2 + 4] = *(const f4*)(src + 4);
        }
        __syncthreads();
#pragma unroll 4
        for (int k = 0; k < 32; ++k) {
            f4 a0 = *(const f4*)&Wt[k][4 * to];
            f4 a1 = *(const f4*)&Wt[k][64 + 4 * to];
            f4 xv = *(const f4*)&Xs[k][4 * tn];
#pragma unroll
            for (int i = 0; i < 4; ++i)
#pragma unroll
                for (int j = 0; j < 4; ++j) {
                    acc[i][j]     += a0[i] * xv[j];
                    acc[4 + i][j] += a1[i] * xv[j];
                }
        }
        __syncthreads();
    }
#pragma unroll
    for (int g = 0; g < 2; ++g)
#pragma unroll
        for (int i = 0; i < 4; ++i) {
            const int o = bo0 + g * 64 + 4 * to + i;
            const float bb_ = bias ? bias[o] : 0.f;
            f4 r;
#pragma unroll
            for (int j = 0; j < 4; ++j) r[j] = scale * acc[g * 4 + i][j] + bb_;
            *(f4*)(Out + ((size_t)b * CC + o) * NN + bn0 + 4 * tn) = r;
        }
}

// ---------------- K3: rsum[b][n] += sum_m exp2(e'[n][m] - SHIFT)   (e' = y'^T y')
// grid (2, NN/128, BB), block 256
__global__ __launch_bounds__(256)
void rowsum_kernel(const float* __restrict__ Y, float* __restrict__ Rsum)
{
    __shared__ float yn[32][132];
    __shared__ float ym[32][132];
    __shared__ float red[128][16];
    const int tid    = threadIdx.x;
    const int mstart = blockIdx.x * (NN / 2);
    const int gn0    = blockIdx.y * 128;
    const int b      = blockIdx.z;
    const int tn = tid & 15;   // n = 4*tn+i, 64+4*tn+i
    const int tm = tid >> 4;   // m = 4*tm+j, 64+4*tm+j
    const float* Yb = Y + (size_t)b * CC * NN;

    float rowpart[8];
#pragma unroll
    for (int i = 0; i < 8; ++i) rowpart[i] = 0.f;

    for (int gm0 = mstart; gm0 < mstart + NN / 2; gm0 += 128) {
        float e[8][8];
#pragma unroll
        for (int i = 0; i < 8; ++i)
#pragma unroll
            for (int j = 0; j < 8; ++j) e[i][j] = 0.f;

        for (int c0 = 0; c0 < CC; c0 += 32) {
            __syncthreads();
            {
                const int sk = tid >> 3;
                const int sn = (tid & 7) << 4;
                const float* srcn = Yb + (size_t)(c0 + sk) * NN + gn0 + sn;
                const float* srcm = Yb + (size_t)(c0 + sk) * NN + gm0 + sn;
#pragma unroll
                for (int q = 0; q < 4; ++q)
                    *(f4*)&yn[sk][sn + 4 * q] = *(const f4*)(srcn + 4 * q);
#pragma unroll
                for (int q = 0; q < 4; ++q)
                    *(f4*)&ym[sk][sn + 4 * q] = *(const f4*)(srcm + 4 * q);
            }
            __syncthreads();
#pragma unroll 4
            for (int k = 0; k < 32; ++k) {
                f4 a0 = *(const f4*)&yn[k][4 * tn];
                f4 a1 = *(const f4*)&yn[k][64 + 4 * tn];
                f4 b0 = *(const f4*)&ym[k][4 * tm];
                f4 b1 = *(const f4*)&ym[k][64 + 4 * tm];
#pragma unroll
                for (int i = 0; i < 4; ++i)
#pragma unroll
                    for (int j = 0; j < 4; ++j) {
                        e[i][j]         += a0[i] * b0[j];
                        e[i][4 + j]     += a0[i] * b1[j];
                        e[4 + i][j]     += a1[i] * b0[j];
                        e[4 + i][4 + j] += a1[i] * b1[j];
                    }
            }
        }
#pragma unroll
        for (int i = 0; i < 8; ++i) {
            float s = 0.f;
#pragma unroll
            for (int j = 0; j < 8; ++j) s += __builtin_amdgcn_exp2f(e[i][j] - SHIFT);
            rowpart[i] += s;
        }
    }
#pragma unroll
    for (int i = 0; i < 8; ++i) {
        const int nl = (i < 4) ? (4 * tn + i) : (64 + 4 * tn + (i - 4));
        red[nl][tm] = rowpart[i];
    }
    __syncthreads();
    if (tid < 128) {
        float s = 0.f;
#pragma unroll
        for (int t = 0; t < 16; ++t) s += red[tid][t];
        atomicAdd(&Rsum[(size_t)b * NN + gn0 + tid], s);
    }
}

// ---------------- K4: out pass. Block owns m-tile(64), loops all n tiles(128):
//   e block -> w = exp2(e'-SHIFT)*rinv[n] -> LDS, colsum partials, PV accumulate.
// grid (NN/64, BB), block 256
__global__ __launch_bounds__(256)
void out_kernel(const float* __restrict__ Y, const float* __restrict__ V,
                const float* __restrict__ Rsum, float* __restrict__ Out)
{
    __shared__ float uA[6400];        // yn[32][132] @0 ; ym[32][68] @4224 ; vt[16][260] overlays @0
    __shared__ float wS[128 * 68];    // w[n_local][m]
    __shared__ float rinvS[128];
    __shared__ float redS[64 * 16];
    __shared__ float colS[64];
    float* yn  = uA;
    float* ymS = uA + 32 * 132;
    float* vtS = uA;

    const int tid = threadIdx.x;
    const int gm0 = blockIdx.x * 64;
    const int b   = blockIdx.y;
    const int tn = tid & 15;  // e-phase rows: n = 4*tn+i, 64+4*tn+i
    const int tm = tid >> 4;  // e-phase cols: m = 4*tm+j
    const int tc = tid & 31;  // pv rows: c = 4*tc+i, 128+4*tc+i
    const int tq = tid >> 5;  // pv cols: m = 4*tq+j, 32+4*tq+j
    const float* Yb = Y + (size_t)b * CC * NN;
    const float* Vb = V + (size_t)b * CC * NN;

    float oacc[8][8];
#pragma unroll
    for (int i = 0; i < 8; ++i)
#pragma unroll
        for (int j = 0; j < 8; ++j) oacc[i][j] = 0.f;
    float colpart[4];
#pragma unroll
    for (int j = 0; j < 4; ++j) colpart[j] = 0.f;

    for (int gn0 = 0; gn0 < NN; gn0 += 128) {
        if (tid < 128) rinvS[tid] = 1.f / Rsum[(size_t)b * NN + gn0 + tid];
        float e[8][4];
#pragma unroll
        for (int i = 0; i < 8; ++i)
#pragma unroll
            for (int j = 0; j < 4; ++j) e[i][j] = 0.f;

        for (int c0 = 0; c0 < CC; c0 += 32) {
            __syncthreads();   // prev consumers of uA/wS done
            {
                const int sk = tid >> 3;
                const int sn = (tid & 7) << 4;
                const float* srcn = Yb + (size_t)(c0 + sk) * NN + gn0 + sn;
#pragma unroll
                for (int q = 0; q < 4; ++q)
                    *(f4*)&yn[sk * 132 + sn + 4 * q] = *(const f4*)(srcn + 4 * q);
                const int sm = (tid & 7) << 3;
                const float* srcm = Yb + (size_t)(c0 + sk) * NN + gm0 + sm;
#pragma unroll
                for (int q = 0; q < 2; ++q)
                    *(f4*)&ymS[sk * 68 + sm + 4 * q] = *(const f4*)(srcm + 4 * q);
            }
            __syncthreads();
#pragma unroll 4
            for (int k = 0; k < 32; ++k) {
                f4 a0 = *(const f4*)&yn[k * 132 + 4 * tn];
                f4 a1 = *(const f4*)&yn[k * 132 + 64 + 4 * tn];
                f4 bm = *(const f4*)&ymS[k * 68 + 4 * tm];
#pragma unroll
                for (int i = 0; i < 4; ++i)
#pragma unroll
                    for (int j = 0; j < 4; ++j) {
                        e[i][j]     += a0[i] * bm[j];
                        e[4 + i][j] += a1[i] * bm[j];
                    }
            }
        }
        __syncthreads();
        // w phase: w[n][m] = exp2(e' - SHIFT) * rinv[n]
#pragma unroll
        for (int i = 0; i < 8; ++i) {
            const int nl = (i < 4) ? (4 * tn + i) : (64 + 4 * tn + (i - 4));
            const float ri = rinvS[nl];
#pragma unroll
            for (int j = 0; j < 4; ++j) {
                const float wv = __builtin_amdgcn_exp2f(e[i][j] - SHIFT) * ri;
                wS[nl * 68 + 4 * tm + j] = wv;
                colpart[j] += wv;
            }
        }
        __syncthreads();
        // PV: oacc[c][m] += sum_n v[c][n] * w[n][m], n chunks of 16
        for (int kc = 0; kc < 128; kc += 16) {
            __syncthreads();
            {
                const float* src = Vb + (size_t)tid * NN + gn0 + kc;
                f4 v0 = *(const f4*)(src + 0);
                f4 v1 = *(const f4*)(src + 4);
                f4 v2 = *(const f4*)(src + 8);
                f4 v3 = *(const f4*)(src + 12);
#pragma unroll
                for (int q = 0; q < 4; ++q) {
                    vtS[(q)      * 260 + tid] = v0[q];
                    vtS[(4 + q)  * 260 + tid] = v1[q];
                    vtS[(8 + q)  * 260 + tid] = v2[q];
                    vtS[(12 + q) * 260 + tid] = v3[q];
                }
            }
            __syncthreads();
#pragma unroll 4
            for (int k2 = 0; k2 < 16; ++k2) {
                f4 vc0 = *(const f4*)&vtS[k2 * 260 + 4 * tc];
                f4 vc1 = *(const f4*)&vtS[k2 * 260 + 128 + 4 * tc];
                const int wrow = kc + k2;
                f4 w0 = *(const f4*)&wS[wrow * 68 + 4 * tq];
                f4 w1 = *(const f4*)&wS[wrow * 68 + 32 + 4 * tq];
#pragma unroll
                for (int i = 0; i < 4; ++i)
#pragma unroll
                    for (int j = 0; j < 4; ++j) {
                        oacc[i][j]         += vc0[i] * w0[j];
                        oacc[i][4 + j]     += vc0[i] * w1[j];
                        oacc[4 + i][j]     += vc1[i] * w0[j];
                        oacc[4 + i][4 + j] += vc1[i] * w1[j];
                    }
            }
        }
    }
    // colsum reduce across tn groups; scale = 1/((1e-9+colsum)*sqrt(C))
#pragma unroll
    for (int j = 0; j < 4; ++j) redS[(4 * tm + j) * 16 + tn] = colpart[j];
    __syncthreads();
    if (tid < 64) {
        float s = 0.f;
#pragma unroll
        for (int t = 0; t < 16; ++t) s += redS[tid * 16 + t];
        colS[tid] = 1.f / ((1e-9f + s) * 16.0f);
    }
    __syncthreads();
    // epilogue
#pragma unroll
    for (int i = 0; i < 8; ++i) {
        const int ccc = (i < 4) ? (4 * tc + i) : (128 + 4 * tc + (i - 4));
        float* orow = Out + ((size_t)b * CC + ccc) * NN + gm0;
#pragma unroll
        for (int g = 0; g < 2; ++g) {
            const int m0 = g * 32 + 4 * tq;
            f4 r;
#pragma unroll
            for (int j = 0; j < 4; ++j) r[j] = oacc[i][g * 4 + j] * colS[m0 + j];
            *(f4*)(orow + m0) = r;
        }
    }
}

extern "C" void kernel_launch(void* const* d_in, const int* in_sizes, int n_in,
                              void* d_out, int out_size, void* d_ws, size_t ws_size,
                              hipStream_t stream)
{
    const float* x   = (const float*)d_in[0];
    const float* Wqk = (const float*)d_in[1];
    const float* Wv  = (const float*)d_in[2];
    const float* bv  = (const float*)d_in[3];
    float* out = (float*)d_out;

    float* y    = (float*)d_ws;
    float* v    = y + (size_t)BB * CC * NN;
    float* rsum = v + (size_t)BB * CC * NN;

    hipMemsetAsync(rsum, 0, (size_t)BB * NN * sizeof(float), stream);

    dim3 blk(256);
    // y' = sqrt(log2e) * Wqk x   (so y'^T y' = log2(e) * energy)
    proj_kernel<<<dim3(NN / 64, CC / 128, BB), blk, 0, stream>>>(x, Wqk, nullptr, y, SQRT_LOG2E);
    // v = Wv x + bv
    proj_kernel<<<dim3(NN / 64, CC / 128, BB), blk, 0, stream>>>(x, Wv, bv, v, 1.0f);

    rowsum_kernel<<<dim3(2, NN / 128, BB), blk, 0, stream>>>(y, rsum);
    out_kernel<<<dim3(NN / 64, BB), blk, 0, stream>>>(y, v, rsum, out);
}

// Round 2
// 380.706 us; speedup vs baseline: 3.9486x; 3.9486x over previous
//
#include <hip/hip_runtime.h>

// SA_Layer offset-attention, MI355X. B=16, C=256, N=2048.
// Round 2: energy + PV on fp16 MFMA (v_mfma_f32_16x16x32_f16); proj stays fp32 VALU.
// ws layout: yt16[B][N][C] fp16 | v16[B][C][N] fp16 | rsum[B][N] f32  (~33.7 MB)

#define BB 16
#define CC 256
#define NN 2048

typedef float f4 __attribute__((ext_vector_type(4)));
typedef _Float16 h8 __attribute__((ext_vector_type(8)));
typedef _Float16 h4 __attribute__((ext_vector_type(4)));

#define SQRT_LOG2E 1.2011224087864498f  // yt = sqrt(log2e)*y  =>  yt.yt = log2(e)*energy
#define WSHIFT 128.0f                   // constant softmax shift (e' <= ~170, safe in f32 accum)

#define MFMA16(a, b, c) __builtin_amdgcn_mfma_f32_16x16x32_f16(a, b, c, 0, 0, 0)

// ---------------- K1: projection (fp32 VALU, exact)
// MODE 0: Out_t[b][n][o] = scale * sum_c W[o][c] X[b][c][n]            (transposed, fp16)
// MODE 1: Out  [b][o][n] = sum_c W[o][c] X[b][c][n] + bias[o]          (fp16)
// grid (NN/64, CC/128, BB), block 256
template <int MODE>
__global__ __launch_bounds__(256)
void proj_kernel(const float* __restrict__ X, const float* __restrict__ W,
                 const float* __restrict__ bias, _Float16* __restrict__ Out, float scale)
{
    __shared__ float Wt[32][132];
    __shared__ float Xs[32][68];
    const int tid = threadIdx.x;
    const int bn0 = blockIdx.x * 64;
    const int bo0 = blockIdx.y * 128;
    const int b   = blockIdx.z;
    const int to = tid & 15;
    const int tn = tid >> 4;
    const float* Xb = X + (size_t)b * CC * NN;

    float acc[8][4];
#pragma unroll
    for (int i = 0; i < 8; ++i)
#pragma unroll
        for (int j = 0; j < 4; ++j) acc[i][j] = 0.f;

    for (int c0 = 0; c0 < CC; c0 += 32) {
        {
            const int o_l = tid >> 1;
            const int cb  = (tid & 1) * 16;
            const float* src = W + (size_t)(bo0 + o_l) * CC + c0 + cb;
            f4 w0 = *(const f4*)(src + 0);
            f4 w1 = *(const f4*)(src + 4);
            f4 w2 = *(const f4*)(src + 8);
            f4 w3 = *(const f4*)(src + 12);
#pragma unroll
            for (int q = 0; q < 4; ++q) {
                Wt[cb + q][o_l]      = w0[q];
                Wt[cb + 4 + q][o_l]  = w1[q];
                Wt[cb + 8 + q][o_l]  = w2[q];
                Wt[cb + 12 + q][o_l] = w3[q];
            }
        }
        {
            const int idx = tid * 8;
            const int k   = idx >> 6;
            const int nn2 = idx & 63;
            const float* src = Xb + (size_t)(c0 + k) * NN + bn0 + nn2;
            *(f4*)&Xs[k][nn2]     = *(const f4*)(src);
            *(f4*)&Xs[k][nn2 + 4] = *(const f4*)(src + 4);
        }
        __syncthreads();
#pragma unroll 4
        for (int k = 0; k < 32; ++k) {
            f4 a0 = *(const f4*)&Wt[k][4 * to];
            f4 a1 = *(const f4*)&Wt[k][64 + 4 * to];
            f4 xv = *(const f4*)&Xs[k][4 * tn];
#pragma unroll
            for (int i = 0; i < 4; ++i)
#pragma unroll
                for (int j = 0; j < 4; ++j) {
                    acc[i][j]     += a0[i] * xv[j];
                    acc[4 + i][j] += a1[i] * xv[j];
                }
        }
        __syncthreads();
    }
    if (MODE == 0) {
        // transposed: Out[(b*NN + n)*CC + o], 4 consecutive o per store
#pragma unroll
        for (int j = 0; j < 4; ++j) {
            const int n = bn0 + 4 * tn + j;
#pragma unroll
            for (int g = 0; g < 2; ++g) {
                h4 r;
#pragma unroll
                for (int i = 0; i < 4; ++i) r[i] = (_Float16)(scale * acc[g * 4 + i][j]);
                *(h4*)(Out + ((size_t)b * NN + n) * CC + bo0 + g * 64 + 4 * to) = r;
            }
        }
    } else {
#pragma unroll
        for (int g = 0; g < 2; ++g)
#pragma unroll
            for (int i = 0; i < 4; ++i) {
                const int o = bo0 + g * 64 + 4 * to + i;
                const float bb_ = bias[o];
                h4 r;
#pragma unroll
                for (int j = 0; j < 4; ++j) r[j] = (_Float16)(acc[g * 4 + i][j] + bb_);
                *(h4*)(Out + ((size_t)b * CC + o) * NN + bn0 + 4 * tn) = r;
            }
    }
}

// ---------------- K2: rsum[b][n] += sum_m exp2(e'[n][m] - WSHIFT), e' = yt.yt^T (fp16 MFMA)
// grid (2 m-halves, NN/256, BB), block 512 (8 waves: 4 n-rows x 2 m-cols)
__global__ __launch_bounds__(512, 2)
void rowsum_f16(const _Float16* __restrict__ YT, float* __restrict__ Rsum)
{
    __shared__ _Float16 ynR[256 * 256];   // row n: 512B, swizzled ^((n&7)<<4)
    __shared__ _Float16 ymC[128 * 40];    // row m: 80B (64B data + pad)
    __shared__ float    rowred[256 * 2];

    const int tid  = threadIdx.x;
    const int wid  = tid >> 6, lane = tid & 63;
    const int l15  = lane & 15, lg = lane >> 4;
    const int wr   = wid >> 1, wc = wid & 1;
    const int mh   = blockIdx.x;
    const int gn0  = blockIdx.y * 256;
    const int b    = blockIdx.z;
    const _Float16* Yb = YT + (size_t)b * NN * CC;
    char* ynB = (char*)ynR;
    char* ymB = (char*)ymC;

    // resident yn slice: 256 rows x 256 c, swizzled
#pragma unroll
    for (int q = 0; q < 16; ++q) {
        const int id = tid * 16 + q;
        const int n = id >> 5, cq = id & 31;
        h8 g = *(const h8*)(Yb + (size_t)(gn0 + n) * CC + cq * 8);
        *(h8*)(ynB + n * 512 + ((cq * 16) ^ ((n & 7) << 4))) = g;
    }

    float rp[4][4];
#pragma unroll
    for (int i = 0; i < 4; ++i)
#pragma unroll
        for (int r = 0; r < 4; ++r) rp[i][r] = 0.f;

    for (int ms = 0; ms < 8; ++ms) {
        const int m0 = mh * 1024 + ms * 128;
        f4 eacc[4][4];
#pragma unroll
        for (int i = 0; i < 4; ++i)
#pragma unroll
            for (int j = 0; j < 4; ++j) eacc[i][j] = (f4){0.f, 0.f, 0.f, 0.f};

        for (int c0 = 0; c0 < CC; c0 += 32) {
            __syncthreads();
#pragma unroll
            for (int q = 0; q < 2; ++q) {
                const int id = tid * 2 + q;
                const int m = id >> 2, cq = id & 3;
                h8 g = *(const h8*)(Yb + (size_t)(m0 + m) * CC + c0 + cq * 8);
                *(h8*)(ymB + m * 80 + cq * 16) = g;
            }
            __syncthreads();
            h8 a[4], bm[4];
#pragma unroll
            for (int nt = 0; nt < 4; ++nt) {
                const int n = wr * 64 + nt * 16 + l15;
                a[nt] = *(const h8*)(ynB + n * 512 + ((c0 * 2 + lg * 16) ^ ((n & 7) << 4)));
            }
#pragma unroll
            for (int mt = 0; mt < 4; ++mt)
                bm[mt] = *(const h8*)(ymB + (wc * 64 + mt * 16 + l15) * 80 + lg * 16);
#pragma unroll
            for (int nt = 0; nt < 4; ++nt)
#pragma unroll
                for (int mt = 0; mt < 4; ++mt)
                    eacc[nt][mt] = MFMA16(a[nt], bm[mt], eacc[nt][mt]);
        }
#pragma unroll
        for (int nt = 0; nt < 4; ++nt)
#pragma unroll
            for (int r = 0; r < 4; ++r) {
                float s = 0.f;
#pragma unroll
                for (int mt = 0; mt < 4; ++mt)
                    s += __builtin_amdgcn_exp2f(eacc[nt][mt][r] - WSHIFT);
                rp[nt][r] += s;
            }
    }
    // reduce over the 16 lanes sharing (lg): bits 0..3
#pragma unroll
    for (int nt = 0; nt < 4; ++nt)
#pragma unroll
        for (int r = 0; r < 4; ++r) {
            float v = rp[nt][r];
            v += __shfl_xor(v, 1);
            v += __shfl_xor(v, 2);
            v += __shfl_xor(v, 4);
            v += __shfl_xor(v, 8);
            rp[nt][r] = v;
        }
    if (l15 == 0) {
#pragma unroll
        for (int nt = 0; nt < 4; ++nt)
#pragma unroll
            for (int r = 0; r < 4; ++r)
                rowred[(wr * 64 + nt * 16 + lg * 4 + r) * 2 + wc] = rp[nt][r];
    }
    __syncthreads();
    if (tid < 256)
        atomicAdd(&Rsum[(size_t)b * NN + gn0 + tid], rowred[tid * 2] + rowred[tid * 2 + 1]);
}

// ---------------- K3: out pass (fp16 MFMA). Block owns 128 out-columns, streams n in 256-steps:
//   e = yn.ym^T (MFMA) -> w = exp2(e'-WSHIFT)*rinv[n] -> fp16 wT (2 halves) -> PV MFMA.
// grid (NN/128, BB), block 512 (8 waves: e-phase 4n x 2m; PV 4c x 2m)
__global__ __launch_bounds__(512, 2)
void out_f16(const _Float16* __restrict__ YT, const _Float16* __restrict__ V16,
             const float* __restrict__ Rsum, float* __restrict__ Out)
{
    __shared__ _Float16 ymS[128 * 256];  // row m: 512B, swizzled ^((m&7)<<4)  (resident)
    __shared__ _Float16 ynS[256 * 40];   // row n: 80B (64B data + pad)
    __shared__ _Float16 wTS[128 * 128];  // row m: 256B, swizzled  (one 128-n half)
    __shared__ _Float16 vS[256 * 64];    // row c: 128B, swizzled
    __shared__ float    rinvS[256];

    const int tid  = threadIdx.x;
    const int wid  = tid >> 6, lane = tid & 63;
    const int l15  = lane & 15, lg = lane >> 4;
    const int wr   = wid >> 1, wc = wid & 1;
    const int gm0  = blockIdx.x * 128;
    const int b    = blockIdx.y;
    const _Float16* Yb = YT + (size_t)b * NN * CC;
    const _Float16* Vb = V16 + (size_t)b * CC * NN;
    char* ymB = (char*)ymS;
    char* ynB = (char*)ynS;
    char* wTB = (char*)wTS;
    char* vB  = (char*)vS;

    // resident ym panel: rows gm0..gm0+127 of yt, full C
#pragma unroll
    for (int q = 0; q < 8; ++q) {
        const int id = tid * 8 + q;
        const int m = id >> 5, cq = id & 31;
        h8 g = *(const h8*)(Yb + (size_t)(gm0 + m) * CC + cq * 8);
        *(h8*)(ymB + m * 512 + ((cq * 16) ^ ((m & 7) << 4))) = g;
    }

    f4 oacc[4][4];
#pragma unroll
    for (int i = 0; i < 4; ++i)
#pragma unroll
        for (int j = 0; j < 4; ++j) oacc[i][j] = (f4){0.f, 0.f, 0.f, 0.f};
    float colpart[4] = {0.f, 0.f, 0.f, 0.f};

    for (int gn0 = 0; gn0 < NN; gn0 += 256) {
        __syncthreads();  // prev PV reads done; rinv free
        if (tid < 256) rinvS[tid] = 1.0f / Rsum[(size_t)b * NN + gn0 + tid];

        // ---- e-phase: e[256n][128m] accumulated in regs (wave: 64n x 64m)
        f4 eacc[4][4];
#pragma unroll
        for (int i = 0; i < 4; ++i)
#pragma unroll
            for (int j = 0; j < 4; ++j) eacc[i][j] = (f4){0.f, 0.f, 0.f, 0.f};

        for (int c0 = 0; c0 < CC; c0 += 32) {
            __syncthreads();
#pragma unroll
            for (int q = 0; q < 2; ++q) {
                const int id = tid * 2 + q;
                const int n = id >> 2, cq = id & 3;
                h8 g = *(const h8*)(Yb + (size_t)(gn0 + n) * CC + c0 + cq * 8);
                *(h8*)(ynB + n * 80 + cq * 16) = g;
            }
            __syncthreads();
            h8 a[4], bm[4];
#pragma unroll
            for (int nt = 0; nt < 4; ++nt)
                a[nt] = *(const h8*)(ynB + (wr * 64 + nt * 16 + l15) * 80 + lg * 16);
#pragma unroll
            for (int mt = 0; mt < 4; ++mt) {
                const int m = wc * 64 + mt * 16 + l15;
                bm[mt] = *(const h8*)(ymB + m * 512 + ((c0 * 2 + lg * 16) ^ ((m & 7) << 4)));
            }
#pragma unroll
            for (int nt = 0; nt < 4; ++nt)
#pragma unroll
                for (int mt = 0; mt < 4; ++mt)
                    eacc[nt][mt] = MFMA16(a[nt], bm[mt], eacc[nt][mt]);
        }

        // ---- w + PV, two 128-n halves
#pragma unroll
        for (int h = 0; h < 2; ++h) {
            __syncthreads();  // previous PV reads of wTS done
            if ((wr >> 1) == h) {
#pragma unroll
                for (int nt = 0; nt < 4; ++nt)
#pragma unroll
                    for (int mt = 0; mt < 4; ++mt) {
                        const int m   = wc * 64 + mt * 16 + l15;
                        const int nis = wr * 64 + nt * 16 + lg * 4;        // n within step
                        const int nb  = (wr & 1) * 64 + nt * 16 + lg * 4;  // n within half
                        f4 e = eacc[nt][mt];
                        const float w0 = __builtin_amdgcn_exp2f(e[0] - WSHIFT) * rinvS[nis + 0];
                        const float w1 = __builtin_amdgcn_exp2f(e[1] - WSHIFT) * rinvS[nis + 1];
                        const float w2 = __builtin_amdgcn_exp2f(e[2] - WSHIFT) * rinvS[nis + 2];
                        const float w3 = __builtin_amdgcn_exp2f(e[3] - WSHIFT) * rinvS[nis + 3];
                        colpart[mt] += w0 + w1 + w2 + w3;
                        h4 hw;
                        hw[0] = (_Float16)w0; hw[1] = (_Float16)w1;
                        hw[2] = (_Float16)w2; hw[3] = (_Float16)w3;
                        *(h4*)(wTB + m * 256 + ((nb * 2) ^ ((m & 7) << 4))) = hw;
                    }
            }
            __syncthreads();  // wTS ready
#pragma unroll
            for (int nc = 0; nc < 128; nc += 64) {
                __syncthreads();  // prev PV chunk reads of vS done
#pragma unroll
                for (int q = 0; q < 4; ++q) {
                    const int id = tid * 4 + q;
                    const int c = id >> 3, nq = id & 7;
                    h8 g = *(const h8*)(Vb + (size_t)c * NN + gn0 + h * 128 + nc + nq * 8);
                    *(h8*)(vB + c * 128 + ((nq * 16) ^ ((c & 7) << 4))) = g;
                }
                __syncthreads();
#pragma unroll
                for (int k2 = 0; k2 < 2; ++k2) {
                    h8 va[4], wb[4];
#pragma unroll
                    for (int ct = 0; ct < 4; ++ct) {
                        const int c = wr * 64 + ct * 16 + l15;
                        va[ct] = *(const h8*)(vB + c * 128 + ((k2 * 64 + lg * 16) ^ ((c & 7) << 4)));
                    }
#pragma unroll
                    for (int mt = 0; mt < 4; ++mt) {
                        const int m = wc * 64 + mt * 16 + l15;
                        wb[mt] = *(const h8*)(wTB + m * 256 + (((nc + k2 * 32 + lg * 8) * 2) ^ ((m & 7) << 4)));
                    }
#pragma unroll
                    for (int ct = 0; ct < 4; ++ct)
#pragma unroll
                        for (int mt = 0; mt < 4; ++mt)
                            oacc[ct][mt] = MFMA16(va[ct], wb[mt], oacc[ct][mt]);
                }
            }
        }
    }

    // ---- colsum reduce: colpart over lg groups -> LDS -> colS[m]
#pragma unroll
    for (int mt = 0; mt < 4; ++mt) {
        colpart[mt] += __shfl_xor(colpart[mt], 16);
        colpart[mt] += __shfl_xor(colpart[mt], 32);
    }
    __syncthreads();
    float* colred = (float*)ynB;  // [128][4] — ynS no longer needed
    if (lane < 16) {
#pragma unroll
        for (int mt = 0; mt < 4; ++mt)
            colred[(wc * 64 + mt * 16 + l15) * 4 + wr] = colpart[mt];
    }
    __syncthreads();
    float* colS = rinvS;  // reuse
    if (tid < 128) {
        const float* cr = colred + tid * 4;
        const float s = cr[0] + cr[1] + cr[2] + cr[3];
        colS[tid] = 1.0f / ((1e-9f + s) * 16.0f);  // 16 = sqrt(C)
    }
    __syncthreads();

    // ---- epilogue: scale by colS, store
#pragma unroll
    for (int mt = 0; mt < 4; ++mt) {
        const float sc = colS[wc * 64 + mt * 16 + l15];
#pragma unroll
        for (int ct = 0; ct < 4; ++ct)
#pragma unroll
            for (int r = 0; r < 4; ++r) {
                const int c = wr * 64 + ct * 16 + lg * 4 + r;
                Out[((size_t)b * CC + c) * NN + gm0 + wc * 64 + mt * 16 + l15] =
                    oacc[ct][mt][r] * sc;
            }
    }
}

extern "C" void kernel_launch(void* const* d_in, const int* in_sizes, int n_in,
                              void* d_out, int out_size, void* d_ws, size_t ws_size,
                              hipStream_t stream)
{
    const float* x   = (const float*)d_in[0];
    const float* Wqk = (const float*)d_in[1];
    const float* Wv  = (const float*)d_in[2];
    const float* bv  = (const float*)d_in[3];
    float* out = (float*)d_out;

    _Float16* yt16 = (_Float16*)d_ws;
    _Float16* v16  = yt16 + (size_t)BB * NN * CC;
    float*    rsum = (float*)(v16 + (size_t)BB * CC * NN);

    hipMemsetAsync(rsum, 0, (size_t)BB * NN * sizeof(float), stream);

    dim3 blk256(256);
    proj_kernel<0><<<dim3(NN / 64, CC / 128, BB), blk256, 0, stream>>>(x, Wqk, nullptr, yt16, SQRT_LOG2E);
    proj_kernel<1><<<dim3(NN / 64, CC / 128, BB), blk256, 0, stream>>>(x, Wv, bv, v16, 1.0f);

    rowsum_f16<<<dim3(2, NN / 256, BB), dim3(512), 0, stream>>>(yt16, rsum);
    out_f16<<<dim3(NN / 128, BB), dim3(512), 0, stream>>>(yt16, v16, rsum, out);
}

// Round 3
// 349.795 us; speedup vs baseline: 4.2976x; 1.0884x over previous
//
#include <hip/hip_runtime.h>

// SA_Layer offset-attention, MI355X. B=16, C=256, N=2048.
// Round 3: everything on fp16 MFMA. proj = split-fp16 (exact to ~2^-22);
// rowsum uses energy symmetry (triangular tiles); out = 2 blocks/CU.
// ws: xh,xl [B][N][C] | Wh,Wl [512][256] | yt [B][N][C] | v [B][C][N] | rsum [B][N]

#define BB 16
#define CC 256
#define NN 2048

typedef float f4 __attribute__((ext_vector_type(4)));
typedef _Float16 h8 __attribute__((ext_vector_type(8)));
typedef _Float16 h4 __attribute__((ext_vector_type(4)));

#define SQRT_LOG2E 1.2011224087864498f  // folded into Wqk: e' = log2(e)*energy
#define WSHIFT 128.0f                   // constant softmax shift (|e'| <= ~170)
#define MFMA16(a, b, c) __builtin_amdgcn_mfma_f32_16x16x32_f16(a, b, c, 0, 0, 0)

// ---------------- K0a: W -> stacked hi/lo fp16. o<256: sqrt_log2e*Wqk; o>=256: Wv.
// grid (512), block 64
__global__ __launch_bounds__(64)
void convw_kernel(const float* __restrict__ Wqk, const float* __restrict__ Wv,
                  _Float16* __restrict__ Wh, _Float16* __restrict__ Wl)
{
    const int o = blockIdx.x;
    const int t = threadIdx.x;
    const float s = (o < CC) ? SQRT_LOG2E : 1.0f;
    const float* src = (o < CC) ? (Wqk + (size_t)o * CC) : (Wv + (size_t)(o - CC) * CC);
    f4 w = *(const f4*)(src + t * 4);
    h4 hh, hl;
#pragma unroll
    for (int q = 0; q < 4; ++q) {
        float v = s * w[q];
        _Float16 h = (_Float16)v;
        hh[q] = h;
        hl[q] = (_Float16)(v - (float)h);
    }
    *(h4*)(Wh + (size_t)o * CC + t * 4) = hh;
    *(h4*)(Wl + (size_t)o * CC + t * 4) = hl;
}

// ---------------- K0b: x[b][c][n] -> xT hi/lo fp16 [b][n][c]
// grid (NN/64, CC/64, BB), block 256
__global__ __launch_bounds__(256)
void transx_kernel(const float* __restrict__ X, _Float16* __restrict__ Xh,
                   _Float16* __restrict__ Xl)
{
    __shared__ float T[64][65];
    const int t = threadIdx.x;
    const int n0 = blockIdx.x * 64, c0 = blockIdx.y * 64, b = blockIdx.z;
    const float* Xb = X + (size_t)b * CC * NN;
    const int nq = (t & 15) * 4;
    const int cl = t >> 4;
#pragma unroll
    for (int cp = 0; cp < 64; cp += 16) {
        f4 v = *(const f4*)(Xb + (size_t)(c0 + cp + cl) * NN + n0 + nq);
#pragma unroll
        for (int q = 0; q < 4; ++q) T[nq + q][cp + cl] = v[q];
    }
    __syncthreads();
    const int n = t & 63, cq = (t >> 6) * 16;
    _Float16* dh = Xh + ((size_t)b * NN + n0 + n) * CC + c0 + cq;
    _Float16* dl = Xl + ((size_t)b * NN + n0 + n) * CC + c0 + cq;
#pragma unroll
    for (int g = 0; g < 2; ++g) {
        h8 hh, hl;
#pragma unroll
        for (int q = 0; q < 8; ++q) {
            float v = T[n][cq + g * 8 + q];
            _Float16 h = (_Float16)v;
            hh[q] = h;
            hl[q] = (_Float16)(v - (float)h);
        }
        *(h8*)(dh + g * 8) = hh;
        *(h8*)(dl + g * 8) = hl;
    }
}

// ---------------- K1: proj GEMM, split-fp16 MFMA. Stacked o: [0,256)=y (transposed out),
// [256,512)=v (+bias). tile 128o x 256n, K=256 chunks of 32.
// grid (NN/256, 4, BB), block 512
__global__ __launch_bounds__(512, 4)
void proj_kernel(const _Float16* __restrict__ Xh, const _Float16* __restrict__ Xl,
                 const _Float16* __restrict__ Wh, const _Float16* __restrict__ Wl,
                 const float* __restrict__ bv, _Float16* __restrict__ Yt,
                 _Float16* __restrict__ V)
{
    __shared__ char L[65536];   // stage: Wh@0[128][80] Wl@10240 Xh@20480[256][80] Xl@40960; epi tile overlays @0
    __shared__ float bbS[128];
    const int tid = threadIdx.x;
    const int lane = tid & 63, wid = tid >> 6;
    const int l15 = lane & 15, lg = lane >> 4;
    const int wo = wid >> 2, wn = wid & 3;   // wave tile 64o x 64n
    const int n0 = blockIdx.x * 256;
    const int bo0 = blockIdx.y * 128;
    const int b = blockIdx.z;
    const bool isV = (blockIdx.y >= 2);
    const _Float16* xh = Xh + (size_t)b * NN * CC;
    const _Float16* xl = Xl + (size_t)b * NN * CC;

    if (isV && tid < 128) bbS[tid] = bv[bo0 - 256 + tid];

    f4 acc[4][4];
#pragma unroll
    for (int i = 0; i < 4; ++i)
#pragma unroll
        for (int j = 0; j < 4; ++j) acc[i][j] = (f4){0.f, 0.f, 0.f, 0.f};

    for (int c0 = 0; c0 < CC; c0 += 32) {
        __syncthreads();
#pragma unroll
        for (int q = 0; q < 2; ++q) {   // W: 1024 slots of 16B
            int id = tid * 2 + q;
            int arr = id >> 9, o = (id >> 2) & 127, s = id & 3;
            const _Float16* src = (arr ? Wl : Wh) + (size_t)(bo0 + o) * CC + c0 + s * 8;
            *(h8*)(L + arr * 10240 + o * 80 + s * 16) = *(const h8*)src;
        }
#pragma unroll
        for (int q = 0; q < 4; ++q) {   // X: 2048 slots
            int id = tid * 4 + q;
            int arr = id >> 10, n = (id >> 2) & 255, s = id & 3;
            const _Float16* src = (arr ? xl : xh) + (size_t)(n0 + n) * CC + c0 + s * 8;
            *(h8*)(L + 20480 + arr * 20480 + n * 80 + s * 16) = *(const h8*)src;
        }
        __syncthreads();
        h8 awh[4], awl[4];
#pragma unroll
        for (int oi = 0; oi < 4; ++oi) {
            int o = wo * 64 + oi * 16 + l15;
            awh[oi] = *(const h8*)(L + o * 80 + lg * 16);
            awl[oi] = *(const h8*)(L + 10240 + o * 80 + lg * 16);
        }
#pragma unroll
        for (int nj = 0; nj < 4; ++nj) {
            int n = wn * 64 + nj * 16 + l15;
            h8 bxh = *(const h8*)(L + 20480 + n * 80 + lg * 16);
            h8 bxl = *(const h8*)(L + 40960 + n * 80 + lg * 16);
#pragma unroll
            for (int oi = 0; oi < 4; ++oi) {
                acc[oi][nj] = MFMA16(awh[oi], bxh, acc[oi][nj]);
                acc[oi][nj] = MFMA16(awh[oi], bxl, acc[oi][nj]);
                acc[oi][nj] = MFMA16(awl[oi], bxh, acc[oi][nj]);
            }
        }
    }
    __syncthreads();
    if (!isV) {
        // epi tile [256 n][128 o] fp16, rows 256B, XOR ((n&7)<<4)
#pragma unroll
        for (int oi = 0; oi < 4; ++oi)
#pragma unroll
            for (int nj = 0; nj < 4; ++nj) {
                int n = wn * 64 + nj * 16 + l15;
                int o = wo * 64 + oi * 16 + lg * 4;
                h4 r;
#pragma unroll
                for (int q = 0; q < 4; ++q) r[q] = (_Float16)acc[oi][nj][q];
                *(h4*)(L + n * 256 + ((o * 2) ^ ((n & 7) << 4))) = r;
            }
        __syncthreads();
        int n = tid >> 1, oh = (tid & 1) * 64;
        _Float16* dst = Yt + ((size_t)b * NN + n0 + n) * CC + bo0 + oh;
#pragma unroll
        for (int k = 0; k < 8; ++k)
            *(h8*)(dst + k * 8) = *(const h8*)(L + n * 256 + (((oh + k * 8) * 2) ^ ((n & 7) << 4)));
    } else {
        // epi tile [128 o][256 n] fp16, rows 512B, XOR ((o&7)<<4)
#pragma unroll
        for (int oi = 0; oi < 4; ++oi)
#pragma unroll
            for (int nj = 0; nj < 4; ++nj) {
                int n = wn * 64 + nj * 16 + l15;
                int ob = wo * 64 + oi * 16 + lg * 4;
                f4 bb4 = *(const f4*)&bbS[ob];
#pragma unroll
                for (int r = 0; r < 4; ++r) {
                    int o = ob + r;
                    *(_Float16*)(L + o * 512 + ((n * 2) ^ ((o & 7) << 4))) =
                        (_Float16)(acc[oi][nj][r] + bb4[r]);
                }
            }
        __syncthreads();
        int o = tid >> 2, nq = (tid & 3) * 64;
        _Float16* dst = V + ((size_t)b * CC + bo0 - 256 + o) * NN + n0 + nq;
#pragma unroll
        for (int k = 0; k < 8; ++k)
            *(h8*)(dst + k * 8) = *(const h8*)(L + o * 512 + (((nq + k * 8) * 2) ^ ((o & 7) << 4)));
    }
}

// ---------------- K2: rsum via symmetric triangular 128x128 tiles.
// Tile (I,J), I<=J: exp(e) row-sums -> rsum[I-range]; col-sums -> rsum[J-range] (skip if I==J).
// grid (136, BB), block 512 (waves: 4n x 2m; wave tile 32n x 64m)
__global__ __launch_bounds__(512, 4)
void rowsum_kernel(const _Float16* __restrict__ Yt, float* __restrict__ Rsum)
{
    __shared__ char L[36864];        // A@0 [128][144], B@18432 [128][144]
    __shared__ float rowred[128][2];
    __shared__ float colred[128][4];
    const int tid = threadIdx.x, lane = tid & 63, wid = tid >> 6;
    const int l15 = lane & 15, lg = lane >> 4;
    const int wn = wid >> 1, wm = wid & 1;
    int idx = blockIdx.x, I = 0;
    while (idx >= 16 - I) { idx -= 16 - I; ++I; }
    const int J = I + idx;
    const int b = blockIdx.y;
    const int nI0 = I * 128, nJ0 = J * 128;
    const _Float16* Yb = Yt + (size_t)b * NN * CC;

    f4 eacc[2][4];
#pragma unroll
    for (int i = 0; i < 2; ++i)
#pragma unroll
        for (int j = 0; j < 4; ++j) eacc[i][j] = (f4){0.f, 0.f, 0.f, 0.f};

    for (int c0 = 0; c0 < CC; c0 += 64) {
        __syncthreads();
#pragma unroll
        for (int q = 0; q < 4; ++q) {   // 2048 slots
            int id = tid * 4 + q;
            int p = id >> 10, r = (id >> 3) & 127, s = id & 7;
            int gn = (p ? nJ0 : nI0) + r;
            *(h8*)(L + p * 18432 + r * 144 + s * 16) = *(const h8*)(Yb + (size_t)gn * CC + c0 + s * 8);
        }
        __syncthreads();
#pragma unroll
        for (int kk = 0; kk < 2; ++kk) {
            h8 a[2], bmf[4];
#pragma unroll
            for (int nt = 0; nt < 2; ++nt) {
                int n = wn * 32 + nt * 16 + l15;
                a[nt] = *(const h8*)(L + n * 144 + kk * 64 + lg * 16);
            }
#pragma unroll
            for (int mt = 0; mt < 4; ++mt) {
                int m = wm * 64 + mt * 16 + l15;
                bmf[mt] = *(const h8*)(L + 18432 + m * 144 + kk * 64 + lg * 16);
            }
#pragma unroll
            for (int nt = 0; nt < 2; ++nt)
#pragma unroll
                for (int mt = 0; mt < 4; ++mt)
                    eacc[nt][mt] = MFMA16(a[nt], bmf[mt], eacc[nt][mt]);
        }
    }
    float rowp[2][4];
    float colp[4] = {0.f, 0.f, 0.f, 0.f};
#pragma unroll
    for (int nt = 0; nt < 2; ++nt)
#pragma unroll
        for (int r = 0; r < 4; ++r) rowp[nt][r] = 0.f;
#pragma unroll
    for (int nt = 0; nt < 2; ++nt)
#pragma unroll
        for (int mt = 0; mt < 4; ++mt)
#pragma unroll
            for (int r = 0; r < 4; ++r) {
                float p = __builtin_amdgcn_exp2f(eacc[nt][mt][r] - WSHIFT);
                rowp[nt][r] += p;
                colp[mt] += p;
            }
#pragma unroll
    for (int nt = 0; nt < 2; ++nt)
#pragma unroll
        for (int r = 0; r < 4; ++r) {
            float v = rowp[nt][r];
            v += __shfl_xor(v, 1); v += __shfl_xor(v, 2);
            v += __shfl_xor(v, 4); v += __shfl_xor(v, 8);
            if (l15 == 0) rowred[wn * 32 + nt * 16 + lg * 4 + r][wm] = v;
        }
#pragma unroll
    for (int mt = 0; mt < 4; ++mt) {
        float v = colp[mt];
        v += __shfl_xor(v, 16); v += __shfl_xor(v, 32);
        if (lg == 0) colred[wm * 64 + mt * 16 + l15][wn] = v;
    }
    __syncthreads();
    if (tid < 128)
        atomicAdd(&Rsum[(size_t)b * NN + nI0 + tid], rowred[tid][0] + rowred[tid][1]);
    if (I != J && tid >= 128 && tid < 256) {
        int m = tid - 128;
        atomicAdd(&Rsum[(size_t)b * NN + nJ0 + m],
                  colred[m][0] + colred[m][1] + colred[m][2] + colred[m][3]);
    }
}

// ---------------- K3: out pass. Block owns 64 m-cols; n-steps of 256:
//   e = yn.ym^T -> w = exp2(e'-WSHIFT)*rinv -> fp16 wT (overlays yn/ym) -> PV (A=wT, B=v).
// grid (512) remapped XCD-aware, block 512
__global__ __launch_bounds__(512, 4)
void out_kernel(const _Float16* __restrict__ Yt, const _Float16* __restrict__ V,
                const float* __restrict__ Rsum, float* __restrict__ Out)
{
    __shared__ char U[46080];    // yn@0 [256][144]=36864 ; ym@36864 [64][144]=9216 ; wT overlays @0 [64][528]=33792
    __shared__ char VS[20480];   // v [256][80]
    __shared__ float rinvS[256];
    __shared__ float colred[64][4];
    __shared__ float colS[64];

    const int tid = threadIdx.x, lane = tid & 63, wid = tid >> 6;
    const int l15 = lane & 15, lg = lane >> 4;
    const int wn = wid >> 1, wm = wid & 1;    // e-phase: 4n(64) x 2m(32)
    const int wmp = wid >> 2, wc = wid & 3;   // PV: 2m(32) x 4c(64)
    const int id = blockIdx.x;
    const int xcd = id & 7, j = id >> 3;
    const int b = xcd * 2 + (j >> 5);         // each XCD -> 2 batches (L2 locality)
    const int gm0 = (j & 31) * 64;
    const _Float16* Yb = Yt + (size_t)b * NN * CC;
    const _Float16* Vb = V + (size_t)b * CC * NN;

    f4 oacc[2][4];
#pragma unroll
    for (int i = 0; i < 2; ++i)
#pragma unroll
        for (int jj = 0; jj < 4; ++jj) oacc[i][jj] = (f4){0.f, 0.f, 0.f, 0.f};
    float colpart[2] = {0.f, 0.f};

    for (int gn0 = 0; gn0 < NN; gn0 += 256) {
        if (tid < 256) rinvS[tid] = 1.0f / Rsum[(size_t)b * NN + gn0 + tid];
        f4 eacc[4][2];
#pragma unroll
        for (int i = 0; i < 4; ++i)
#pragma unroll
            for (int jj = 0; jj < 2; ++jj) eacc[i][jj] = (f4){0.f, 0.f, 0.f, 0.f};

        for (int c0 = 0; c0 < CC; c0 += 64) {
            __syncthreads();    // prev MFMA reads of U done (incl. prev step's wT)
#pragma unroll
            for (int q = 0; q < 4; ++q) {   // yn: 2048 slots
                int sid = tid * 4 + q;
                int n = sid >> 3, s = sid & 7;
                *(h8*)(U + n * 144 + s * 16) = *(const h8*)(Yb + (size_t)(gn0 + n) * CC + c0 + s * 8);
            }
            {   // ym: 512 slots
                int m = tid >> 3, s = tid & 7;
                *(h8*)(U + 36864 + m * 144 + s * 16) = *(const h8*)(Yb + (size_t)(gm0 + m) * CC + c0 + s * 8);
            }
            __syncthreads();
#pragma unroll
            for (int kk = 0; kk < 2; ++kk) {
                h8 a[4], bmf[2];
#pragma unroll
                for (int nt = 0; nt < 4; ++nt) {
                    int n = wn * 64 + nt * 16 + l15;
                    a[nt] = *(const h8*)(U + n * 144 + kk * 64 + lg * 16);
                }
#pragma unroll
                for (int mt = 0; mt < 2; ++mt) {
                    int m = wm * 32 + mt * 16 + l15;
                    bmf[mt] = *(const h8*)(U + 36864 + m * 144 + kk * 64 + lg * 16);
                }
#pragma unroll
                for (int nt = 0; nt < 4; ++nt)
#pragma unroll
                    for (int mt = 0; mt < 2; ++mt)
                        eacc[nt][mt] = MFMA16(a[nt], bmf[mt], eacc[nt][mt]);
            }
        }
        __syncthreads();   // e reads done; U free for wT
        // w-phase: w[n][m] = exp2(e'-WSHIFT)*rinv[n]; wT[64m][256n] rows 528B
#pragma unroll
        for (int nt = 0; nt < 4; ++nt)
#pragma unroll
            for (int mt = 0; mt < 2; ++mt) {
                int nb = wn * 64 + nt * 16 + lg * 4;
                int m = wm * 32 + mt * 16 + l15;
                f4 e = eacc[nt][mt];
                f4 rv = *(const f4*)&rinvS[nb];
                float w0 = __builtin_amdgcn_exp2f(e[0] - WSHIFT) * rv[0];
                float w1 = __builtin_amdgcn_exp2f(e[1] - WSHIFT) * rv[1];
                float w2 = __builtin_amdgcn_exp2f(e[2] - WSHIFT) * rv[2];
                float w3 = __builtin_amdgcn_exp2f(e[3] - WSHIFT) * rv[3];
                colpart[mt] += w0 + w1 + w2 + w3;
                h4 hw;
                hw[0] = (_Float16)w0; hw[1] = (_Float16)w1;
                hw[2] = (_Float16)w2; hw[3] = (_Float16)w3;
                *(h4*)(U + m * 528 + nb * 2) = hw;
            }
        __syncthreads();   // wT ready
        // PV: 8 n-chunks of 32
        for (int kc = 0; kc < 8; ++kc) {
            __syncthreads();    // prev chunk VS reads done
#pragma unroll
            for (int q = 0; q < 2; ++q) {   // VS: 1024 slots
                int sid = tid * 2 + q;
                int c = sid >> 2, s = sid & 3;
                *(h8*)(VS + c * 80 + s * 16) = *(const h8*)(Vb + (size_t)c * NN + gn0 + kc * 32 + s * 8);
            }
            __syncthreads();
            h8 aw[2], bvf[4];
#pragma unroll
            for (int mf = 0; mf < 2; ++mf) {
                int m = wmp * 32 + mf * 16 + l15;
                aw[mf] = *(const h8*)(U + m * 528 + kc * 64 + lg * 16);
            }
#pragma unroll
            for (int cf = 0; cf < 4; ++cf) {
                int c = wc * 64 + cf * 16 + l15;
                bvf[cf] = *(const h8*)(VS + c * 80 + lg * 16);
            }
#pragma unroll
            for (int mf = 0; mf < 2; ++mf)
#pragma unroll
                for (int cf = 0; cf < 4; ++cf)
                    oacc[mf][cf] = MFMA16(aw[mf], bvf[cf], oacc[mf][cf]);
        }
    }
    // colsum reduce
#pragma unroll
    for (int mt = 0; mt < 2; ++mt) {
        float v = colpart[mt];
        v += __shfl_xor(v, 16); v += __shfl_xor(v, 32);
        if (lg == 0) colred[wm * 32 + mt * 16 + l15][wn] = v;
    }
    __syncthreads();
    if (tid < 64) {
        float s = colred[tid][0] + colred[tid][1] + colred[tid][2] + colred[tid][3];
        colS[tid] = 1.0f / ((1e-9f + s) * 16.0f);   // 16 = sqrt(C)
    }
    __syncthreads();
    // epilogue: f4 stores, 4 consecutive m per lane
#pragma unroll
    for (int mf = 0; mf < 2; ++mf)
#pragma unroll
        for (int cf = 0; cf < 4; ++cf) {
            int m0 = wmp * 32 + mf * 16 + lg * 4;
            int c = wc * 64 + cf * 16 + l15;
            f4 sc = *(const f4*)&colS[m0];
            f4 r;
#pragma unroll
            for (int q = 0; q < 4; ++q) r[q] = oacc[mf][cf][q] * sc[q];
            *(f4*)(Out + ((size_t)b * CC + c) * NN + gm0 + m0) = r;
        }
}

extern "C" void kernel_launch(void* const* d_in, const int* in_sizes, int n_in,
                              void* d_out, int out_size, void* d_ws, size_t ws_size,
                              hipStream_t stream)
{
    const float* x   = (const float*)d_in[0];
    const float* Wqk = (const float*)d_in[1];
    const float* Wv  = (const float*)d_in[2];
    const float* bv  = (const float*)d_in[3];
    float* out = (float*)d_out;

    const size_t NE = (size_t)BB * NN * CC;   // 8.39M elems
    _Float16* xh = (_Float16*)d_ws;
    _Float16* xl = xh + NE;
    _Float16* wh = xl + NE;                   // [512][256]
    _Float16* wl = wh + (size_t)512 * CC;
    _Float16* yt = wl + (size_t)512 * CC;     // [B][N][C]
    _Float16* v  = yt + NE;                   // [B][C][N]
    float* rsum  = (float*)(v + NE);          // [B][N]

    hipMemsetAsync(rsum, 0, (size_t)BB * NN * sizeof(float), stream);

    convw_kernel<<<dim3(512), dim3(64), 0, stream>>>(Wqk, Wv, wh, wl);
    transx_kernel<<<dim3(NN / 64, CC / 64, BB), dim3(256), 0, stream>>>(x, xh, xl);
    proj_kernel<<<dim3(NN / 256, 4, BB), dim3(512), 0, stream>>>(xh, xl, wh, wl, bv, yt, v);
    rowsum_kernel<<<dim3(136, BB), dim3(512), 0, stream>>>(yt, rsum);
    out_kernel<<<dim3(512), dim3(512), 0, stream>>>(yt, v, rsum, out);
}

// Round 4
// 308.737 us; speedup vs baseline: 4.8691x; 1.1330x over previous
//
#include <hip/hip_runtime.h>

// SA_Layer offset-attention, MI355X. B=16, C=256, N=2048.
// Round 4: split fused out into epass (e-GEMM + softmax-w -> W fp16 in ws, colsum)
// and pv (pure GEMM with colsum-scale epilogue). glds + XOR-swizzled LDS.
// ws: [ region: W(chunk)+colsum | aliases xh,xl ] [ yt | v | wh | wl | rsum ]

#define BB 16
#define CC 256
#define NN 2048

typedef float f4 __attribute__((ext_vector_type(4)));
typedef _Float16 h8 __attribute__((ext_vector_type(8)));
typedef _Float16 h4 __attribute__((ext_vector_type(4)));
typedef unsigned int u32;

#define SQRT_LOG2E 1.2011224087864498f  // folded into Wqk: e' = log2(e)*energy
#define WSHIFT 128.0f                   // constant softmax shift (|e'| <= ~170)
#define MFMA16(a, b, c) __builtin_amdgcn_mfma_f32_16x16x32_f16(a, b, c, 0, 0, 0)

__device__ __forceinline__ void glds16(const void* g, void* l) {
    __builtin_amdgcn_global_load_lds(
        (const __attribute__((address_space(1))) u32*)g,
        (__attribute__((address_space(3))) u32*)l, 16, 0, 0);
}

// ---------------- K0a: W -> stacked hi/lo fp16. o<256: sqrt_log2e*Wqk; o>=256: Wv.
__global__ __launch_bounds__(64)
void convw_kernel(const float* __restrict__ Wqk, const float* __restrict__ Wv,
                  _Float16* __restrict__ Wh, _Float16* __restrict__ Wl)
{
    const int o = blockIdx.x;
    const int t = threadIdx.x;
    const float s = (o < CC) ? SQRT_LOG2E : 1.0f;
    const float* src = (o < CC) ? (Wqk + (size_t)o * CC) : (Wv + (size_t)(o - CC) * CC);
    f4 w = *(const f4*)(src + t * 4);
    h4 hh, hl;
#pragma unroll
    for (int q = 0; q < 4; ++q) {
        float v = s * w[q];
        _Float16 h = (_Float16)v;
        hh[q] = h;
        hl[q] = (_Float16)(v - (float)h);
    }
    *(h4*)(Wh + (size_t)o * CC + t * 4) = hh;
    *(h4*)(Wl + (size_t)o * CC + t * 4) = hl;
}

// ---------------- K0b: x[b][c][n] -> xT hi/lo fp16 [b][n][c]
__global__ __launch_bounds__(256)
void transx_kernel(const float* __restrict__ X, _Float16* __restrict__ Xh,
                   _Float16* __restrict__ Xl)
{
    __shared__ float T[64][65];
    const int t = threadIdx.x;
    const int n0 = blockIdx.x * 64, c0 = blockIdx.y * 64, b = blockIdx.z;
    const float* Xb = X + (size_t)b * CC * NN;
    const int nq = (t & 15) * 4;
    const int cl = t >> 4;
#pragma unroll
    for (int cp = 0; cp < 64; cp += 16) {
        f4 v = *(const f4*)(Xb + (size_t)(c0 + cp + cl) * NN + n0 + nq);
#pragma unroll
        for (int q = 0; q < 4; ++q) T[nq + q][cp + cl] = v[q];
    }
    __syncthreads();
    const int n = t & 63, cq = (t >> 6) * 16;
    _Float16* dh = Xh + ((size_t)b * NN + n0 + n) * CC + c0 + cq;
    _Float16* dl = Xl + ((size_t)b * NN + n0 + n) * CC + c0 + cq;
#pragma unroll
    for (int g = 0; g < 2; ++g) {
        h8 hh, hl;
#pragma unroll
        for (int q = 0; q < 8; ++q) {
            float v = T[n][cq + g * 8 + q];
            _Float16 h = (_Float16)v;
            hh[q] = h;
            hl[q] = (_Float16)(v - (float)h);
        }
        *(h8*)(dh + g * 8) = hh;
        *(h8*)(dl + g * 8) = hl;
    }
}

// ---------------- K1: proj GEMM, split-fp16 MFMA (verbatim round 3)
__global__ __launch_bounds__(512, 4)
void proj_kernel(const _Float16* __restrict__ Xh, const _Float16* __restrict__ Xl,
                 const _Float16* __restrict__ Wh, const _Float16* __restrict__ Wl,
                 const float* __restrict__ bv, _Float16* __restrict__ Yt,
                 _Float16* __restrict__ V)
{
    __shared__ char L[65536];
    __shared__ float bbS[128];
    const int tid = threadIdx.x;
    const int lane = tid & 63, wid = tid >> 6;
    const int l15 = lane & 15, lg = lane >> 4;
    const int wo = wid >> 2, wn = wid & 3;
    const int n0 = blockIdx.x * 256;
    const int bo0 = blockIdx.y * 128;
    const int b = blockIdx.z;
    const bool isV = (blockIdx.y >= 2);
    const _Float16* xh = Xh + (size_t)b * NN * CC;
    const _Float16* xl = Xl + (size_t)b * NN * CC;

    if (isV && tid < 128) bbS[tid] = bv[bo0 - 256 + tid];

    f4 acc[4][4];
#pragma unroll
    for (int i = 0; i < 4; ++i)
#pragma unroll
        for (int j = 0; j < 4; ++j) acc[i][j] = (f4){0.f, 0.f, 0.f, 0.f};

    for (int c0 = 0; c0 < CC; c0 += 32) {
        __syncthreads();
#pragma unroll
        for (int q = 0; q < 2; ++q) {
            int id = tid * 2 + q;
            int arr = id >> 9, o = (id >> 2) & 127, s = id & 3;
            const _Float16* src = (arr ? Wl : Wh) + (size_t)(bo0 + o) * CC + c0 + s * 8;
            *(h8*)(L + arr * 10240 + o * 80 + s * 16) = *(const h8*)src;
        }
#pragma unroll
        for (int q = 0; q < 4; ++q) {
            int id = tid * 4 + q;
            int arr = id >> 10, n = (id >> 2) & 255, s = id & 3;
            const _Float16* src = (arr ? xl : xh) + (size_t)(n0 + n) * CC + c0 + s * 8;
            *(h8*)(L + 20480 + arr * 20480 + n * 80 + s * 16) = *(const h8*)src;
        }
        __syncthreads();
        h8 awh[4], awl[4];
#pragma unroll
        for (int oi = 0; oi < 4; ++oi) {
            int o = wo * 64 + oi * 16 + l15;
            awh[oi] = *(const h8*)(L + o * 80 + lg * 16);
            awl[oi] = *(const h8*)(L + 10240 + o * 80 + lg * 16);
        }
#pragma unroll
        for (int nj = 0; nj < 4; ++nj) {
            int n = wn * 64 + nj * 16 + l15;
            h8 bxh = *(const h8*)(L + 20480 + n * 80 + lg * 16);
            h8 bxl = *(const h8*)(L + 40960 + n * 80 + lg * 16);
#pragma unroll
            for (int oi = 0; oi < 4; ++oi) {
                acc[oi][nj] = MFMA16(awh[oi], bxh, acc[oi][nj]);
                acc[oi][nj] = MFMA16(awh[oi], bxl, acc[oi][nj]);
                acc[oi][nj] = MFMA16(awl[oi], bxh, acc[oi][nj]);
            }
        }
    }
    __syncthreads();
    if (!isV) {
#pragma unroll
        for (int oi = 0; oi < 4; ++oi)
#pragma unroll
            for (int nj = 0; nj < 4; ++nj) {
                int n = wn * 64 + nj * 16 + l15;
                int o = wo * 64 + oi * 16 + lg * 4;
                h4 r;
#pragma unroll
                for (int q = 0; q < 4; ++q) r[q] = (_Float16)acc[oi][nj][q];
                *(h4*)(L + n * 256 + ((o * 2) ^ ((n & 7) << 4))) = r;
            }
        __syncthreads();
        int n = tid >> 1, oh = (tid & 1) * 64;
        _Float16* dst = Yt + ((size_t)b * NN + n0 + n) * CC + bo0 + oh;
#pragma unroll
        for (int k = 0; k < 8; ++k)
            *(h8*)(dst + k * 8) = *(const h8*)(L + n * 256 + (((oh + k * 8) * 2) ^ ((n & 7) << 4)));
    } else {
#pragma unroll
        for (int oi = 0; oi < 4; ++oi)
#pragma unroll
            for (int nj = 0; nj < 4; ++nj) {
                int n = wn * 64 + nj * 16 + l15;
                int ob = wo * 64 + oi * 16 + lg * 4;
                f4 bb4 = *(const f4*)&bbS[ob];
#pragma unroll
                for (int r = 0; r < 4; ++r) {
                    int o = ob + r;
                    *(_Float16*)(L + o * 512 + ((n * 2) ^ ((o & 7) << 4))) =
                        (_Float16)(acc[oi][nj][r] + bb4[r]);
                }
            }
        __syncthreads();
        int o = tid >> 2, nq = (tid & 3) * 64;
        _Float16* dst = V + ((size_t)b * CC + bo0 - 256 + o) * NN + n0 + nq;
#pragma unroll
        for (int k = 0; k < 8; ++k)
            *(h8*)(dst + k * 8) = *(const h8*)(L + o * 512 + (((nq + k * 8) * 2) ^ ((o & 7) << 4)));
    }
}

// ---------------- K2: rsum via symmetric triangular 128x128 tiles (verbatim round 3)
__global__ __launch_bounds__(512, 4)
void rowsum_kernel(const _Float16* __restrict__ Yt, float* __restrict__ Rsum)
{
    __shared__ char L[36864];
    __shared__ float rowred[128][2];
    __shared__ float colred[128][4];
    const int tid = threadIdx.x, lane = tid & 63, wid = tid >> 6;
    const int l15 = lane & 15, lg = lane >> 4;
    const int wn = wid >> 1, wm = wid & 1;
    int idx = blockIdx.x, I = 0;
    while (idx >= 16 - I) { idx -= 16 - I; ++I; }
    const int J = I + idx;
    const int b = blockIdx.y;
    const int nI0 = I * 128, nJ0 = J * 128;
    const _Float16* Yb = Yt + (size_t)b * NN * CC;

    f4 eacc[2][4];
#pragma unroll
    for (int i = 0; i < 2; ++i)
#pragma unroll
        for (int j = 0; j < 4; ++j) eacc[i][j] = (f4){0.f, 0.f, 0.f, 0.f};

    for (int c0 = 0; c0 < CC; c0 += 64) {
        __syncthreads();
#pragma unroll
        for (int q = 0; q < 4; ++q) {
            int id = tid * 4 + q;
            int p = id >> 10, r = (id >> 3) & 127, s = id & 7;
            int gn = (p ? nJ0 : nI0) + r;
            *(h8*)(L + p * 18432 + r * 144 + s * 16) = *(const h8*)(Yb + (size_t)gn * CC + c0 + s * 8);
        }
        __syncthreads();
#pragma unroll
        for (int kk = 0; kk < 2; ++kk) {
            h8 a[2], bmf[4];
#pragma unroll
            for (int nt = 0; nt < 2; ++nt) {
                int n = wn * 32 + nt * 16 + l15;
                a[nt] = *(const h8*)(L + n * 144 + kk * 64 + lg * 16);
            }
#pragma unroll
            for (int mt = 0; mt < 4; ++mt) {
                int m = wm * 64 + mt * 16 + l15;
                bmf[mt] = *(const h8*)(L + 18432 + m * 144 + kk * 64 + lg * 16);
            }
#pragma unroll
            for (int nt = 0; nt < 2; ++nt)
#pragma unroll
                for (int mt = 0; mt < 4; ++mt)
                    eacc[nt][mt] = MFMA16(a[nt], bmf[mt], eacc[nt][mt]);
        }
    }
    float rowp[2][4];
    float colp[4] = {0.f, 0.f, 0.f, 0.f};
#pragma unroll
    for (int nt = 0; nt < 2; ++nt)
#pragma unroll
        for (int r = 0; r < 4; ++r) rowp[nt][r] = 0.f;
#pragma unroll
    for (int nt = 0; nt < 2; ++nt)
#pragma unroll
        for (int mt = 0; mt < 4; ++mt)
#pragma unroll
            for (int r = 0; r < 4; ++r) {
                float p = __builtin_amdgcn_exp2f(eacc[nt][mt][r] - WSHIFT);
                rowp[nt][r] += p;
                colp[mt] += p;
            }
#pragma unroll
    for (int nt = 0; nt < 2; ++nt)
#pragma unroll
        for (int r = 0; r < 4; ++r) {
            float v = rowp[nt][r];
            v += __shfl_xor(v, 1); v += __shfl_xor(v, 2);
            v += __shfl_xor(v, 4); v += __shfl_xor(v, 8);
            if (l15 == 0) rowred[wn * 32 + nt * 16 + lg * 4 + r][wm] = v;
        }
#pragma unroll
    for (int mt = 0; mt < 4; ++mt) {
        float v = colp[mt];
        v += __shfl_xor(v, 16); v += __shfl_xor(v, 32);
        if (lg == 0) colred[wm * 64 + mt * 16 + l15][wn] = v;
    }
    __syncthreads();
    if (tid < 128)
        atomicAdd(&Rsum[(size_t)b * NN + nI0 + tid], rowred[tid][0] + rowred[tid][1]);
    if (I != J && tid >= 128 && tid < 256) {
        int m = tid - 128;
        atomicAdd(&Rsum[(size_t)b * NN + nJ0 + m],
                  colred[m][0] + colred[m][1] + colred[m][2] + colred[m][3]);
    }
}

// ---------------- K3: epass — e tile [256n][64m], w = exp2(e'-128)*rinv -> W[m][n] fp16,
// colsum[m] atomics. glds + XOR-swizzled LDS, 2 barriers per 64-c chunk.
// grid (8 n-tiles, 32 m-tiles, Bchunk), block 512 (waves 4n x 2m; wave 64n x 32m)
__global__ __launch_bounds__(512, 4)
void epass_kernel(const _Float16* __restrict__ Yt, const float* __restrict__ Rsum,
                  _Float16* __restrict__ W, float* __restrict__ Colsum, int bstart)
{
    __shared__ char ynS[256 * 128];   // [n][128B], byte ^ ((n&7)<<4)
    __shared__ char ymS[64 * 128];    // [m][128B], byte ^ ((m&7)<<4)
    __shared__ float rinvS[256];
    __shared__ float colred[64][4];

    const int tid = threadIdx.x, lane = tid & 63, wid = tid >> 6;
    const int l15 = lane & 15, lg = lane >> 4;
    const int wn = wid >> 1, wm = wid & 1;
    const int gn0 = blockIdx.x * 256;
    const int gm0 = blockIdx.y * 64;
    const int bc = blockIdx.z;
    const int b = bstart + bc;
    const char* Yb = (const char*)(Yt + (size_t)b * NN * CC);

    if (tid < 256) rinvS[tid] = 1.0f / Rsum[(size_t)b * NN + gn0 + tid];

    f4 eacc[4][2];
#pragma unroll
    for (int i = 0; i < 4; ++i)
#pragma unroll
        for (int j = 0; j < 2; ++j) eacc[i][j] = (f4){0.f, 0.f, 0.f, 0.f};

    for (int c0 = 0; c0 < CC; c0 += 64) {
        __syncthreads();
#pragma unroll
        for (int q = 0; q < 4; ++q) {     // yn: 2048 slots of 16B
            int id = q * 512 + tid;
            int n = id >> 3, s = id & 7;
            glds16(Yb + (size_t)(gn0 + n) * 512 + c0 * 2 + ((s * 16) ^ ((n & 7) << 4)),
                   ynS + id * 16);
        }
        {                                  // ym: 512 slots
            int m = tid >> 3, s = tid & 7;
            glds16(Yb + (size_t)(gm0 + m) * 512 + c0 * 2 + ((s * 16) ^ ((m & 7) << 4)),
                   ymS + tid * 16);
        }
        __syncthreads();
#pragma unroll
        for (int kk = 0; kk < 2; ++kk) {
            h8 a[4], bmf[2];
#pragma unroll
            for (int nt = 0; nt < 4; ++nt) {
                int n = wn * 64 + nt * 16 + l15;
                a[nt] = *(const h8*)(ynS + n * 128 + ((kk * 64 + lg * 16) ^ ((n & 7) << 4)));
            }
#pragma unroll
            for (int mt = 0; mt < 2; ++mt) {
                int m = wm * 32 + mt * 16 + l15;
                bmf[mt] = *(const h8*)(ymS + m * 128 + ((kk * 64 + lg * 16) ^ ((m & 7) << 4)));
            }
#pragma unroll
            for (int nt = 0; nt < 4; ++nt)
#pragma unroll
                for (int mt = 0; mt < 2; ++mt)
                    eacc[nt][mt] = MFMA16(a[nt], bmf[mt], eacc[nt][mt]);
        }
    }

    // epilogue: w = exp2(e'-128)*rinv, write W[m][n], accumulate colsum
    float colp[2] = {0.f, 0.f};
#pragma unroll
    for (int nt = 0; nt < 4; ++nt)
#pragma unroll
        for (int mt = 0; mt < 2; ++mt) {
            const int nl = wn * 64 + nt * 16 + lg * 4;
            const int m = gm0 + wm * 32 + mt * 16 + l15;
            f4 e = eacc[nt][mt];
            f4 rv = *(const f4*)&rinvS[nl];
            float w0 = __builtin_amdgcn_exp2f(e[0] - WSHIFT) * rv[0];
            float w1 = __builtin_amdgcn_exp2f(e[1] - WSHIFT) * rv[1];
            float w2 = __builtin_amdgcn_exp2f(e[2] - WSHIFT) * rv[2];
            float w3 = __builtin_amdgcn_exp2f(e[3] - WSHIFT) * rv[3];
            colp[mt] += w0 + w1 + w2 + w3;
            h4 hw;
            hw[0] = (_Float16)w0; hw[1] = (_Float16)w1;
            hw[2] = (_Float16)w2; hw[3] = (_Float16)w3;
            *(h4*)(W + ((size_t)bc * NN + m) * NN + gn0 + nl) = hw;
        }
#pragma unroll
    for (int mt = 0; mt < 2; ++mt) {
        float v = colp[mt];
        v += __shfl_xor(v, 16); v += __shfl_xor(v, 32);
        if (lg == 0) colred[wm * 32 + mt * 16 + l15][wn] = v;
    }
    __syncthreads();
    if (tid < 64) {
        float s = colred[tid][0] + colred[tid][1] + colred[tid][2] + colred[tid][3];
        atomicAdd(&Colsum[(size_t)b * NN + gm0 + tid], s);
    }
}

// ---------------- K4: pv — pure GEMM out[c][m] = sum_n v[c][n] W[m][n], scale epilogue.
// grid (32, Bchunk) with XCD-chunked bijective remap (c-half pairs share W panel in L2),
// block 512 (waves 2m x 4c; wave 64m x 32c), K-chunk 128, glds + XOR LDS.
__global__ __launch_bounds__(512, 4)
void pv_kernel(const _Float16* __restrict__ V, const _Float16* __restrict__ W,
               const float* __restrict__ Colsum, float* __restrict__ Out, int bstart)
{
    __shared__ char wS[128 * 256];   // [m][256B], byte ^ ((m&7)<<4)
    __shared__ char vS[128 * 256];   // [c][256B], byte ^ ((c&7)<<4)
    __shared__ float colS[128];

    const int tid = threadIdx.x, lane = tid & 63, wid = tid >> 6;
    const int l15 = lane & 15, lg = lane >> 4;
    const int wm = wid >> 2, wc = wid & 3;
    const int total = gridDim.x * gridDim.y;
    const int hw = blockIdx.y * gridDim.x + blockIdx.x;
    const int logical = (hw & 7) * (total >> 3) + (hw >> 3);   // total % 8 == 0
    const int bc = logical >> 5;
    const int idx = logical & 31;
    const int gm0 = (idx >> 1) * 128;
    const int c_base = (idx & 1) * 128;
    const int b = bstart + bc;
    const char* Vb = (const char*)(V + ((size_t)b * CC + c_base) * NN);
    const char* Wb = (const char*)(W + ((size_t)bc * NN + gm0) * NN);

    if (tid < 128) colS[tid] = 1.0f / ((1e-9f + Colsum[(size_t)b * NN + gm0 + tid]) * 16.0f);

    f4 oacc[4][2];
#pragma unroll
    for (int i = 0; i < 4; ++i)
#pragma unroll
        for (int j = 0; j < 2; ++j) oacc[i][j] = (f4){0.f, 0.f, 0.f, 0.f};

    for (int gn0 = 0; gn0 < NN; gn0 += 128) {
        __syncthreads();
#pragma unroll
        for (int q = 0; q < 4; ++q) {     // wS: 2048 slots
            int id = q * 512 + tid;
            int m = id >> 4, s = id & 15;
            glds16(Wb + (size_t)m * (NN * 2) + gn0 * 2 + ((s * 16) ^ ((m & 7) << 4)),
                   wS + id * 16);
        }
#pragma unroll
        for (int q = 0; q < 4; ++q) {     // vS: 2048 slots
            int id = q * 512 + tid;
            int c = id >> 4, s = id & 15;
            glds16(Vb + (size_t)c * (NN * 2) + gn0 * 2 + ((s * 16) ^ ((c & 7) << 4)),
                   vS + id * 16);
        }
        __syncthreads();
#pragma unroll
        for (int kk = 0; kk < 4; ++kk) {
            h8 a[4], bvf[2];
#pragma unroll
            for (int mt = 0; mt < 4; ++mt) {
                int m = wm * 64 + mt * 16 + l15;
                a[mt] = *(const h8*)(wS + m * 256 + ((kk * 64 + lg * 16) ^ ((m & 7) << 4)));
            }
#pragma unroll
            for (int ct = 0; ct < 2; ++ct) {
                int c = wc * 32 + ct * 16 + l15;
                bvf[ct] = *(const h8*)(vS + c * 256 + ((kk * 64 + lg * 16) ^ ((c & 7) << 4)));
            }
#pragma unroll
            for (int mt = 0; mt < 4; ++mt)
#pragma unroll
                for (int ct = 0; ct < 2; ++ct)
                    oacc[mt][ct] = MFMA16(a[mt], bvf[ct], oacc[mt][ct]);
        }
    }

    // epilogue: out[c][m] = oacc * colS[m], coalesced f4 over m
#pragma unroll
    for (int mt = 0; mt < 4; ++mt) {
        const int m0 = wm * 64 + mt * 16 + lg * 4;
        f4 sc = *(const f4*)&colS[m0];
#pragma unroll
        for (int ct = 0; ct < 2; ++ct) {
            const int c = c_base + wc * 32 + ct * 16 + l15;
            f4 r;
#pragma unroll
            for (int q = 0; q < 4; ++q) r[q] = oacc[mt][ct][q] * sc[q];
            *(f4*)(Out + ((size_t)b * CC + c) * NN + gm0 + m0) = r;
        }
    }
}

extern "C" void kernel_launch(void* const* d_in, const int* in_sizes, int n_in,
                              void* d_out, int out_size, void* d_ws, size_t ws_size,
                              hipStream_t stream)
{
    const float* x   = (const float*)d_in[0];
    const float* Wqk = (const float*)d_in[1];
    const float* Wv  = (const float*)d_in[2];
    const float* bv  = (const float*)d_in[3];
    float* out = (float*)d_out;

    const size_t NE   = (size_t)BB * NN * CC;            // 8.39M fp16 elems
    const size_t NEb  = NE * 2;                           // 16,777,216 B
    const size_t WROW = (size_t)NN * NN * 2;              // 8,388,608 B per batch
    const size_t CSB  = (size_t)BB * NN * 4;              // rsum/colsum bytes
    const size_t persist = 2 * NEb + (size_t)512 * CC * 2 * 2 + CSB;

    int Bc = 2;
    for (int cand = 16; cand >= 2; cand >>= 1) {
        size_t reg = (size_t)cand * WROW + CSB;
        if (reg < 2 * NEb) reg = 2 * NEb;
        if (persist + reg <= ws_size) { Bc = cand; break; }
    }
    size_t regsz = (size_t)Bc * WROW + CSB;
    if (regsz < 2 * NEb) regsz = 2 * NEb;

    char* region = (char*)d_ws;
    _Float16* Wbuf   = (_Float16*)region;
    float*    colsum = (float*)(region + (size_t)Bc * WROW);
    _Float16* xh = (_Float16*)region;
    _Float16* xl = xh + NE;
    _Float16* yt = (_Float16*)(region + regsz);
    _Float16* v  = yt + NE;
    _Float16* wh = v + NE;
    _Float16* wl = wh + (size_t)512 * CC;
    float*    rsum = (float*)(wl + (size_t)512 * CC);

    convw_kernel<<<dim3(512), dim3(64), 0, stream>>>(Wqk, Wv, wh, wl);
    transx_kernel<<<dim3(NN / 64, CC / 64, BB), dim3(256), 0, stream>>>(x, xh, xl);
    proj_kernel<<<dim3(NN / 256, 4, BB), dim3(512), 0, stream>>>(xh, xl, wh, wl, bv, yt, v);

    // xh/xl dead now; region reused for W + colsum
    hipMemsetAsync(rsum, 0, CSB, stream);
    hipMemsetAsync(colsum, 0, CSB, stream);

    rowsum_kernel<<<dim3(136, BB), dim3(512), 0, stream>>>(yt, rsum);

    const int nch = BB / Bc;
    for (int ch = 0; ch < nch; ++ch) {
        epass_kernel<<<dim3(8, 32, Bc), dim3(512), 0, stream>>>(yt, rsum, Wbuf, colsum, ch * Bc);
        pv_kernel<<<dim3(32, Bc), dim3(512), 0, stream>>>(v, Wbuf, colsum, out, ch * Bc);
    }
}

// Round 5
// 269.591 us; speedup vs baseline: 5.5761x; 1.1452x over previous
//
#include <hip/hip_runtime.h>

// SA_Layer offset-attention, MI355X. B=16, C=256, N=2048.
// Round 5: fused out2 (e-GEMM -> softmax-w in LDS -> PV) replaces epass+pv;
// W matrix never touches HBM. rowsum moved to glds16 staging.
// ws: xh | xl | wh | wl | yt | v | rsum   (~67.5 MB)

#define BB 16
#define CC 256
#define NN 2048

typedef float f4 __attribute__((ext_vector_type(4)));
typedef _Float16 h8 __attribute__((ext_vector_type(8)));
typedef _Float16 h4 __attribute__((ext_vector_type(4)));
typedef unsigned int u32;

#define SQRT_LOG2E 1.2011224087864498f  // folded into Wqk: e' = log2(e)*energy
#define WSHIFT 128.0f                   // constant softmax shift (|e'| <= ~170)
#define MFMA16(a, b, c) __builtin_amdgcn_mfma_f32_16x16x32_f16(a, b, c, 0, 0, 0)

__device__ __forceinline__ void glds16(const void* g, void* l) {
    __builtin_amdgcn_global_load_lds(
        (const __attribute__((address_space(1))) u32*)g,
        (__attribute__((address_space(3))) u32*)l, 16, 0, 0);
}

// ---------------- K0a: W -> stacked hi/lo fp16. o<256: sqrt_log2e*Wqk; o>=256: Wv.
__global__ __launch_bounds__(64)
void convw_kernel(const float* __restrict__ Wqk, const float* __restrict__ Wv,
                  _Float16* __restrict__ Wh, _Float16* __restrict__ Wl)
{
    const int o = blockIdx.x;
    const int t = threadIdx.x;
    const float s = (o < CC) ? SQRT_LOG2E : 1.0f;
    const float* src = (o < CC) ? (Wqk + (size_t)o * CC) : (Wv + (size_t)(o - CC) * CC);
    f4 w = *(const f4*)(src + t * 4);
    h4 hh, hl;
#pragma unroll
    for (int q = 0; q < 4; ++q) {
        float v = s * w[q];
        _Float16 h = (_Float16)v;
        hh[q] = h;
        hl[q] = (_Float16)(v - (float)h);
    }
    *(h4*)(Wh + (size_t)o * CC + t * 4) = hh;
    *(h4*)(Wl + (size_t)o * CC + t * 4) = hl;
}

// ---------------- K0b: x[b][c][n] -> xT hi/lo fp16 [b][n][c]
__global__ __launch_bounds__(256)
void transx_kernel(const float* __restrict__ X, _Float16* __restrict__ Xh,
                   _Float16* __restrict__ Xl)
{
    __shared__ float T[64][65];
    const int t = threadIdx.x;
    const int n0 = blockIdx.x * 64, c0 = blockIdx.y * 64, b = blockIdx.z;
    const float* Xb = X + (size_t)b * CC * NN;
    const int nq = (t & 15) * 4;
    const int cl = t >> 4;
#pragma unroll
    for (int cp = 0; cp < 64; cp += 16) {
        f4 v = *(const f4*)(Xb + (size_t)(c0 + cp + cl) * NN + n0 + nq);
#pragma unroll
        for (int q = 0; q < 4; ++q) T[nq + q][cp + cl] = v[q];
    }
    __syncthreads();
    const int n = t & 63, cq = (t >> 6) * 16;
    _Float16* dh = Xh + ((size_t)b * NN + n0 + n) * CC + c0 + cq;
    _Float16* dl = Xl + ((size_t)b * NN + n0 + n) * CC + c0 + cq;
#pragma unroll
    for (int g = 0; g < 2; ++g) {
        h8 hh, hl;
#pragma unroll
        for (int q = 0; q < 8; ++q) {
            float v = T[n][cq + g * 8 + q];
            _Float16 h = (_Float16)v;
            hh[q] = h;
            hl[q] = (_Float16)(v - (float)h);
        }
        *(h8*)(dh + g * 8) = hh;
        *(h8*)(dl + g * 8) = hl;
    }
}

// ---------------- K1: proj GEMM, split-fp16 MFMA (verbatim round 3/4)
__global__ __launch_bounds__(512, 4)
void proj_kernel(const _Float16* __restrict__ Xh, const _Float16* __restrict__ Xl,
                 const _Float16* __restrict__ Wh, const _Float16* __restrict__ Wl,
                 const float* __restrict__ bv, _Float16* __restrict__ Yt,
                 _Float16* __restrict__ V)
{
    __shared__ char L[65536];
    __shared__ float bbS[128];
    const int tid = threadIdx.x;
    const int lane = tid & 63, wid = tid >> 6;
    const int l15 = lane & 15, lg = lane >> 4;
    const int wo = wid >> 2, wn = wid & 3;
    const int n0 = blockIdx.x * 256;
    const int bo0 = blockIdx.y * 128;
    const int b = blockIdx.z;
    const bool isV = (blockIdx.y >= 2);
    const _Float16* xh = Xh + (size_t)b * NN * CC;
    const _Float16* xl = Xl + (size_t)b * NN * CC;

    if (isV && tid < 128) bbS[tid] = bv[bo0 - 256 + tid];

    f4 acc[4][4];
#pragma unroll
    for (int i = 0; i < 4; ++i)
#pragma unroll
        for (int j = 0; j < 4; ++j) acc[i][j] = (f4){0.f, 0.f, 0.f, 0.f};

    for (int c0 = 0; c0 < CC; c0 += 32) {
        __syncthreads();
#pragma unroll
        for (int q = 0; q < 2; ++q) {
            int id = tid * 2 + q;
            int arr = id >> 9, o = (id >> 2) & 127, s = id & 3;
            const _Float16* src = (arr ? Wl : Wh) + (size_t)(bo0 + o) * CC + c0 + s * 8;
            *(h8*)(L + arr * 10240 + o * 80 + s * 16) = *(const h8*)src;
        }
#pragma unroll
        for (int q = 0; q < 4; ++q) {
            int id = tid * 4 + q;
            int arr = id >> 10, n = (id >> 2) & 255, s = id & 3;
            const _Float16* src = (arr ? xl : xh) + (size_t)(n0 + n) * CC + c0 + s * 8;
            *(h8*)(L + 20480 + arr * 20480 + n * 80 + s * 16) = *(const h8*)src;
        }
        __syncthreads();
        h8 awh[4], awl[4];
#pragma unroll
        for (int oi = 0; oi < 4; ++oi) {
            int o = wo * 64 + oi * 16 + l15;
            awh[oi] = *(const h8*)(L + o * 80 + lg * 16);
            awl[oi] = *(const h8*)(L + 10240 + o * 80 + lg * 16);
        }
#pragma unroll
        for (int nj = 0; nj < 4; ++nj) {
            int n = wn * 64 + nj * 16 + l15;
            h8 bxh = *(const h8*)(L + 20480 + n * 80 + lg * 16);
            h8 bxl = *(const h8*)(L + 40960 + n * 80 + lg * 16);
#pragma unroll
            for (int oi = 0; oi < 4; ++oi) {
                acc[oi][nj] = MFMA16(awh[oi], bxh, acc[oi][nj]);
                acc[oi][nj] = MFMA16(awh[oi], bxl, acc[oi][nj]);
                acc[oi][nj] = MFMA16(awl[oi], bxh, acc[oi][nj]);
            }
        }
    }
    __syncthreads();
    if (!isV) {
#pragma unroll
        for (int oi = 0; oi < 4; ++oi)
#pragma unroll
            for (int nj = 0; nj < 4; ++nj) {
                int n = wn * 64 + nj * 16 + l15;
                int o = wo * 64 + oi * 16 + lg * 4;
                h4 r;
#pragma unroll
                for (int q = 0; q < 4; ++q) r[q] = (_Float16)acc[oi][nj][q];
                *(h4*)(L + n * 256 + ((o * 2) ^ ((n & 7) << 4))) = r;
            }
        __syncthreads();
        int n = tid >> 1, oh = (tid & 1) * 64;
        _Float16* dst = Yt + ((size_t)b * NN + n0 + n) * CC + bo0 + oh;
#pragma unroll
        for (int k = 0; k < 8; ++k)
            *(h8*)(dst + k * 8) = *(const h8*)(L + n * 256 + (((oh + k * 8) * 2) ^ ((n & 7) << 4)));
    } else {
#pragma unroll
        for (int oi = 0; oi < 4; ++oi)
#pragma unroll
            for (int nj = 0; nj < 4; ++nj) {
                int n = wn * 64 + nj * 16 + l15;
                int ob = wo * 64 + oi * 16 + lg * 4;
                f4 bb4 = *(const f4*)&bbS[ob];
#pragma unroll
                for (int r = 0; r < 4; ++r) {
                    int o = ob + r;
                    *(_Float16*)(L + o * 512 + ((n * 2) ^ ((o & 7) << 4))) =
                        (_Float16)(acc[oi][nj][r] + bb4[r]);
                }
            }
        __syncthreads();
        int o = tid >> 2, nq = (tid & 3) * 64;
        _Float16* dst = V + ((size_t)b * CC + bo0 - 256 + o) * NN + n0 + nq;
#pragma unroll
        for (int k = 0; k < 8; ++k)
            *(h8*)(dst + k * 8) = *(const h8*)(L + o * 512 + (((nq + k * 8) * 2) ^ ((o & 7) << 4)));
    }
}

// ---------------- K2: rsum via symmetric triangular 128x128 tiles, glds16 staging.
// grid (136, BB), block 512 (waves 4n x 2m; wave 32n x 64m)
__global__ __launch_bounds__(512, 4)
void rowsum_kernel(const _Float16* __restrict__ Yt, float* __restrict__ Rsum)
{
    __shared__ char As[16384];    // [128 n][128B], byte-in-row ^ ((n&7)<<4)
    __shared__ char Bs[16384];    // [128 m][128B], byte-in-row ^ ((m&7)<<4)
    __shared__ float rowred[128][2];
    __shared__ float colred[128][4];
    const int tid = threadIdx.x, lane = tid & 63, wid = tid >> 6;
    const int l15 = lane & 15, lg = lane >> 4;
    const int wn = wid >> 1, wm = wid & 1;
    int idx = blockIdx.x, I = 0;
    while (idx >= 16 - I) { idx -= 16 - I; ++I; }
    const int J = I + idx;
    const int b = blockIdx.y;
    const int nI0 = I * 128, nJ0 = J * 128;
    const char* Yb = (const char*)(Yt + (size_t)b * NN * CC);

    f4 eacc[2][4];
#pragma unroll
    for (int i = 0; i < 2; ++i)
#pragma unroll
        for (int j = 0; j < 4; ++j) eacc[i][j] = (f4){0.f, 0.f, 0.f, 0.f};

    for (int c0 = 0; c0 < CC; c0 += 64) {
        __syncthreads();
#pragma unroll
        for (int q = 0; q < 2; ++q) {   // A: 1024 slots of 16B
            int sid = q * 512 + tid;
            int n = sid >> 3, s = sid & 7;
            glds16(Yb + (size_t)(nI0 + n) * 512 + c0 * 2 + ((s * 16) ^ ((n & 7) << 4)),
                   As + sid * 16);
        }
#pragma unroll
        for (int q = 0; q < 2; ++q) {   // B: 1024 slots
            int sid = q * 512 + tid;
            int m = sid >> 3, s = sid & 7;
            glds16(Yb + (size_t)(nJ0 + m) * 512 + c0 * 2 + ((s * 16) ^ ((m & 7) << 4)),
                   Bs + sid * 16);
        }
        __syncthreads();
#pragma unroll
        for (int kk = 0; kk < 2; ++kk) {
            h8 a[2], bmf[4];
#pragma unroll
            for (int nt = 0; nt < 2; ++nt) {
                int n = wn * 32 + nt * 16 + l15;
                a[nt] = *(const h8*)(As + n * 128 + ((kk * 64 + lg * 16) ^ ((n & 7) << 4)));
            }
#pragma unroll
            for (int mt = 0; mt < 4; ++mt) {
                int m = wm * 64 + mt * 16 + l15;
                bmf[mt] = *(const h8*)(Bs + m * 128 + ((kk * 64 + lg * 16) ^ ((m & 7) << 4)));
            }
#pragma unroll
            for (int nt = 0; nt < 2; ++nt)
#pragma unroll
                for (int mt = 0; mt < 4; ++mt)
                    eacc[nt][mt] = MFMA16(a[nt], bmf[mt], eacc[nt][mt]);
        }
    }
    float rowp[2][4];
    float colp[4] = {0.f, 0.f, 0.f, 0.f};
#pragma unroll
    for (int nt = 0; nt < 2; ++nt)
#pragma unroll
        for (int r = 0; r < 4; ++r) rowp[nt][r] = 0.f;
#pragma unroll
    for (int nt = 0; nt < 2; ++nt)
#pragma unroll
        for (int mt = 0; mt < 4; ++mt)
#pragma unroll
            for (int r = 0; r < 4; ++r) {
                float p = __builtin_amdgcn_exp2f(eacc[nt][mt][r] - WSHIFT);
                rowp[nt][r] += p;
                colp[mt] += p;
            }
#pragma unroll
    for (int nt = 0; nt < 2; ++nt)
#pragma unroll
        for (int r = 0; r < 4; ++r) {
            float v = rowp[nt][r];
            v += __shfl_xor(v, 1); v += __shfl_xor(v, 2);
            v += __shfl_xor(v, 4); v += __shfl_xor(v, 8);
            if (l15 == 0) rowred[wn * 32 + nt * 16 + lg * 4 + r][wm] = v;
        }
#pragma unroll
    for (int mt = 0; mt < 4; ++mt) {
        float v = colp[mt];
        v += __shfl_xor(v, 16); v += __shfl_xor(v, 32);
        if (lg == 0) colred[wm * 64 + mt * 16 + l15][wn] = v;
    }
    __syncthreads();
    if (tid < 128)
        atomicAdd(&Rsum[(size_t)b * NN + nI0 + tid], rowred[tid][0] + rowred[tid][1]);
    if (I != J && tid >= 128 && tid < 256) {
        int m = tid - 128;
        atomicAdd(&Rsum[(size_t)b * NN + nJ0 + m],
                  colred[m][0] + colred[m][1] + colred[m][2] + colred[m][3]);
    }
}

// ---------------- K3: fused out2. Block owns (batch, 128-m-tile); streams n in 256-steps:
// e = yn.ym^T (glds, 4 chunks) -> w = exp2(e'-128)*rinv -> fp16 wT in LDS -> PV (A=wT, B=v).
// colsum accumulated in registers across all n (no atomics). grid 256 = 1 block/CU, XCD-pinned.
__global__ __launch_bounds__(512, 2)
void out2_kernel(const _Float16* __restrict__ Yt, const _Float16* __restrict__ V,
                 const float* __restrict__ Rsum, float* __restrict__ Out)
{
    __shared__ char stage[49152];   // e: yn[256][128B]@0, ym[128][128B]@32768 ; PV: v[256][128B]@0
    __shared__ char wT[65536];      // [128 m][512B], byte-in-row ^ ((m&7)<<4)
    __shared__ float rinvS[256];
    __shared__ float colred[128][4];
    __shared__ float colS[128];

    const int tid = threadIdx.x, lane = tid & 63, wid = tid >> 6;
    const int l15 = lane & 15, lg = lane >> 4;
    const int wn = wid >> 1, wm = wid & 1;   // e: wave 64n x 64m ; PV: wave 64c x 64m
    const int id = blockIdx.x;
    const int xcd = id & 7, j = id >> 3;
    const int b = xcd * 2 + (j >> 4);        // 2 batches per XCD (L2 locality)
    const int gm0 = (j & 15) * 128;
    const char* Yb = (const char*)(Yt + (size_t)b * NN * CC);
    const char* Vb = (const char*)(V + (size_t)b * CC * NN);

    f4 oacc[4][4];   // [mt][ct]: reg <-> m (A=wT row), l15 <-> c (B=v row)
#pragma unroll
    for (int i = 0; i < 4; ++i)
#pragma unroll
        for (int jj = 0; jj < 4; ++jj) oacc[i][jj] = (f4){0.f, 0.f, 0.f, 0.f};
    float colp[4] = {0.f, 0.f, 0.f, 0.f};

    for (int gn0 = 0; gn0 < NN; gn0 += 256) {
        // ---- e-phase: e[256n][128m]
        f4 eacc[4][4];
#pragma unroll
        for (int i = 0; i < 4; ++i)
#pragma unroll
            for (int jj = 0; jj < 4; ++jj) eacc[i][jj] = (f4){0.f, 0.f, 0.f, 0.f};

        for (int c0 = 0; c0 < CC; c0 += 64) {
            __syncthreads();   // prev readers of stage/rinv done
            if (c0 == 0 && tid < 256)
                rinvS[tid] = 1.0f / Rsum[(size_t)b * NN + gn0 + tid];
#pragma unroll
            for (int q = 0; q < 4; ++q) {   // yn: 2048 slots of 16B
                int sid = q * 512 + tid;
                int n = sid >> 3, s = sid & 7;
                glds16(Yb + (size_t)(gn0 + n) * 512 + c0 * 2 + ((s * 16) ^ ((n & 7) << 4)),
                       stage + sid * 16);
            }
#pragma unroll
            for (int q = 0; q < 2; ++q) {   // ym: 1024 slots
                int sid = q * 512 + tid;
                int m = sid >> 3, s = sid & 7;
                glds16(Yb + (size_t)(gm0 + m) * 512 + c0 * 2 + ((s * 16) ^ ((m & 7) << 4)),
                       stage + 32768 + sid * 16);
            }
            __syncthreads();
#pragma unroll
            for (int kk = 0; kk < 2; ++kk) {
                h8 a[4], bmf[4];
#pragma unroll
                for (int nt = 0; nt < 4; ++nt) {
                    int n = wn * 64 + nt * 16 + l15;
                    a[nt] = *(const h8*)(stage + n * 128 + ((kk * 64 + lg * 16) ^ ((n & 7) << 4)));
                }
#pragma unroll
                for (int mt = 0; mt < 4; ++mt) {
                    int m = wm * 64 + mt * 16 + l15;
                    bmf[mt] = *(const h8*)(stage + 32768 + m * 128 + ((kk * 64 + lg * 16) ^ ((m & 7) << 4)));
                }
#pragma unroll
                for (int nt = 0; nt < 4; ++nt)
#pragma unroll
                    for (int mt = 0; mt < 4; ++mt)
                        eacc[nt][mt] = MFMA16(a[nt], bmf[mt], eacc[nt][mt]);
            }
        }

        // ---- w-phase: w[n][m] = exp2(e'-WSHIFT)*rinv[n] -> wT[m][n] fp16 in LDS
#pragma unroll
        for (int nt = 0; nt < 4; ++nt)
#pragma unroll
            for (int mt = 0; mt < 4; ++mt) {
                const int nl = wn * 64 + nt * 16 + lg * 4;
                const int m = wm * 64 + mt * 16 + l15;
                f4 e = eacc[nt][mt];
                f4 rv = *(const f4*)&rinvS[nl];
                float w0 = __builtin_amdgcn_exp2f(e[0] - WSHIFT) * rv[0];
                float w1 = __builtin_amdgcn_exp2f(e[1] - WSHIFT) * rv[1];
                float w2 = __builtin_amdgcn_exp2f(e[2] - WSHIFT) * rv[2];
                float w3 = __builtin_amdgcn_exp2f(e[3] - WSHIFT) * rv[3];
                colp[mt] += w0 + w1 + w2 + w3;
                h4 hw;
                hw[0] = (_Float16)w0; hw[1] = (_Float16)w1;
                hw[2] = (_Float16)w2; hw[3] = (_Float16)w3;
                *(h4*)(wT + m * 512 + ((nl * 2) ^ ((m & 7) << 4))) = hw;
            }
        __syncthreads();   // wT ready; all waves past e-phase (stage free)

        // ---- PV: out[256c][128m] += v . wT over this step's 256 n, 4 chunks of 64
        for (int kc = 0; kc < 4; ++kc) {
            if (kc) __syncthreads();   // prev chunk reads of stage done
#pragma unroll
            for (int q = 0; q < 4; ++q) {   // v: 2048 slots
                int sid = q * 512 + tid;
                int c = sid >> 3, s = sid & 7;
                glds16(Vb + (size_t)c * (NN * 2) + (gn0 + kc * 64) * 2 + ((s * 16) ^ ((c & 7) << 4)),
                       stage + sid * 16);
            }
            __syncthreads();
#pragma unroll
            for (int kk = 0; kk < 2; ++kk) {
                h8 aw[4], bvf[4];
#pragma unroll
                for (int mt = 0; mt < 4; ++mt) {
                    int m = wm * 64 + mt * 16 + l15;
                    aw[mt] = *(const h8*)(wT + m * 512 + ((kc * 128 + kk * 64 + lg * 16) ^ ((m & 7) << 4)));
                }
#pragma unroll
                for (int ct = 0; ct < 4; ++ct) {
                    int c = wn * 64 + ct * 16 + l15;
                    bvf[ct] = *(const h8*)(stage + c * 128 + ((kk * 64 + lg * 16) ^ ((c & 7) << 4)));
                }
#pragma unroll
                for (int mt = 0; mt < 4; ++mt)
#pragma unroll
                    for (int ct = 0; ct < 4; ++ct)
                        oacc[mt][ct] = MFMA16(aw[mt], bvf[ct], oacc[mt][ct]);
            }
        }
    }

    // ---- colsum reduce (register partials cover all n); scale; store
#pragma unroll
    for (int mt = 0; mt < 4; ++mt) {
        float v = colp[mt];
        v += __shfl_xor(v, 16); v += __shfl_xor(v, 32);
        if (lg == 0) colred[wm * 64 + mt * 16 + l15][wn] = v;
    }
    __syncthreads();
    if (tid < 128) {
        float s = colred[tid][0] + colred[tid][1] + colred[tid][2] + colred[tid][3];
        colS[tid] = 1.0f / ((1e-9f + s) * 16.0f);   // 16 = sqrt(C)
    }
    __syncthreads();
#pragma unroll
    for (int mt = 0; mt < 4; ++mt) {
        const int m0 = wm * 64 + mt * 16 + lg * 4;
        f4 sc = *(const f4*)&colS[m0];
#pragma unroll
        for (int ct = 0; ct < 4; ++ct) {
            const int c = wn * 64 + ct * 16 + l15;
            f4 r;
#pragma unroll
            for (int q = 0; q < 4; ++q) r[q] = oacc[mt][ct][q] * sc[q];
            *(f4*)(Out + ((size_t)b * CC + c) * NN + gm0 + m0) = r;
        }
    }
}

extern "C" void kernel_launch(void* const* d_in, const int* in_sizes, int n_in,
                              void* d_out, int out_size, void* d_ws, size_t ws_size,
                              hipStream_t stream)
{
    const float* x   = (const float*)d_in[0];
    const float* Wqk = (const float*)d_in[1];
    const float* Wv  = (const float*)d_in[2];
    const float* bv  = (const float*)d_in[3];
    float* out = (float*)d_out;

    const size_t NE = (size_t)BB * NN * CC;
    _Float16* xh = (_Float16*)d_ws;
    _Float16* xl = xh + NE;
    _Float16* wh = xl + NE;
    _Float16* wl = wh + (size_t)512 * CC;
    _Float16* yt = wl + (size_t)512 * CC;
    _Float16* v  = yt + NE;
    float* rsum  = (float*)(v + NE);

    hipMemsetAsync(rsum, 0, (size_t)BB * NN * sizeof(float), stream);

    convw_kernel<<<dim3(512), dim3(64), 0, stream>>>(Wqk, Wv, wh, wl);
    transx_kernel<<<dim3(NN / 64, CC / 64, BB), dim3(256), 0, stream>>>(x, xh, xl);
    proj_kernel<<<dim3(NN / 256, 4, BB), dim3(512), 0, stream>>>(xh, xl, wh, wl, bv, yt, v);
    rowsum_kernel<<<dim3(136, BB), dim3(512), 0, stream>>>(yt, rsum);
    out2_kernel<<<dim3(256), dim3(512), 0, stream>>>(yt, v, rsum, out);
}

// Round 6
// 268.476 us; speedup vs baseline: 5.5993x; 1.0042x over previous
//
#include <hip/hip_runtime.h>

// SA_Layer offset-attention, MI355X. B=16, C=256, N=2048.
// Round 6: out2 re-tiled for 2 blocks/CU (m-tile 64, LDS 76KB, VGPR<=128);
// proj converted to glds16+XOR staging with 64-c chunks (2 blocks/CU).
// ws: xh | xl | wh | wl | yt | v | rsum   (~67.5 MB)

#define BB 16
#define CC 256
#define NN 2048

typedef float f4 __attribute__((ext_vector_type(4)));
typedef _Float16 h8 __attribute__((ext_vector_type(8)));
typedef _Float16 h4 __attribute__((ext_vector_type(4)));
typedef unsigned int u32;

#define SQRT_LOG2E 1.2011224087864498f  // folded into Wqk: e' = log2(e)*energy
#define WSHIFT 128.0f                   // constant softmax shift (|e'| <= ~170)
#define MFMA16(a, b, c) __builtin_amdgcn_mfma_f32_16x16x32_f16(a, b, c, 0, 0, 0)

__device__ __forceinline__ void glds16(const void* g, void* l) {
    __builtin_amdgcn_global_load_lds(
        (const __attribute__((address_space(1))) u32*)g,
        (__attribute__((address_space(3))) u32*)l, 16, 0, 0);
}

// ---------------- K0a: W -> stacked hi/lo fp16. o<256: sqrt_log2e*Wqk; o>=256: Wv.
__global__ __launch_bounds__(64)
void convw_kernel(const float* __restrict__ Wqk, const float* __restrict__ Wv,
                  _Float16* __restrict__ Wh, _Float16* __restrict__ Wl)
{
    const int o = blockIdx.x;
    const int t = threadIdx.x;
    const float s = (o < CC) ? SQRT_LOG2E : 1.0f;
    const float* src = (o < CC) ? (Wqk + (size_t)o * CC) : (Wv + (size_t)(o - CC) * CC);
    f4 w = *(const f4*)(src + t * 4);
    h4 hh, hl;
#pragma unroll
    for (int q = 0; q < 4; ++q) {
        float v = s * w[q];
        _Float16 h = (_Float16)v;
        hh[q] = h;
        hl[q] = (_Float16)(v - (float)h);
    }
    *(h4*)(Wh + (size_t)o * CC + t * 4) = hh;
    *(h4*)(Wl + (size_t)o * CC + t * 4) = hl;
}

// ---------------- K0b: x[b][c][n] -> xT hi/lo fp16 [b][n][c]
__global__ __launch_bounds__(256)
void transx_kernel(const float* __restrict__ X, _Float16* __restrict__ Xh,
                   _Float16* __restrict__ Xl)
{
    __shared__ float T[64][65];
    const int t = threadIdx.x;
    const int n0 = blockIdx.x * 64, c0 = blockIdx.y * 64, b = blockIdx.z;
    const float* Xb = X + (size_t)b * CC * NN;
    const int nq = (t & 15) * 4;
    const int cl = t >> 4;
#pragma unroll
    for (int cp = 0; cp < 64; cp += 16) {
        f4 v = *(const f4*)(Xb + (size_t)(c0 + cp + cl) * NN + n0 + nq);
#pragma unroll
        for (int q = 0; q < 4; ++q) T[nq + q][cp + cl] = v[q];
    }
    __syncthreads();
    const int n = t & 63, cq = (t >> 6) * 16;
    _Float16* dh = Xh + ((size_t)b * NN + n0 + n) * CC + c0 + cq;
    _Float16* dl = Xl + ((size_t)b * NN + n0 + n) * CC + c0 + cq;
#pragma unroll
    for (int g = 0; g < 2; ++g) {
        h8 hh, hl;
#pragma unroll
        for (int q = 0; q < 8; ++q) {
            float v = T[n][cq + g * 8 + q];
            _Float16 h = (_Float16)v;
            hh[q] = h;
            hl[q] = (_Float16)(v - (float)h);
        }
        *(h8*)(dh + g * 8) = hh;
        *(h8*)(dl + g * 8) = hl;
    }
}

// ---------------- K1: proj GEMM, split-fp16 MFMA, glds16+XOR staging.
// Stacked o: [0,256)=y (transposed out), [256,512)=v (+bias).
// tile 128o x 128n, K chunks of 64. grid (NN/128, 4, BB), block 512 (waves 2o x 4n).
__global__ __launch_bounds__(512, 4)
void proj_kernel(const _Float16* __restrict__ Xh, const _Float16* __restrict__ Xl,
                 const _Float16* __restrict__ Wh, const _Float16* __restrict__ Wl,
                 const float* __restrict__ bv, _Float16* __restrict__ Yt,
                 _Float16* __restrict__ V)
{
    __shared__ char L[65536];   // Wh@0[128][128B] Wl@16384 Xh@32768[128][128B] Xl@49152; epi overlays @0
    __shared__ float bbS[128];
    const int tid = threadIdx.x;
    const int lane = tid & 63, wid = tid >> 6;
    const int l15 = lane & 15, lg = lane >> 4;
    const int wo = wid >> 2, wn = wid & 3;   // wave tile 64o x 32n
    const int n0 = blockIdx.x * 128;
    const int bo0 = blockIdx.y * 128;
    const int b = blockIdx.z;
    const bool isV = (blockIdx.y >= 2);
    const char* xhB = (const char*)(Xh + (size_t)b * NN * CC);
    const char* xlB = (const char*)(Xl + (size_t)b * NN * CC);
    const char* whB = (const char*)Wh;
    const char* wlB = (const char*)Wl;

    if (isV && tid < 128) bbS[tid] = bv[bo0 - 256 + tid];

    f4 acc[4][2];
#pragma unroll
    for (int i = 0; i < 4; ++i)
#pragma unroll
        for (int j = 0; j < 2; ++j) acc[i][j] = (f4){0.f, 0.f, 0.f, 0.f};

    for (int c0 = 0; c0 < CC; c0 += 64) {
        __syncthreads();
#pragma unroll
        for (int q = 0; q < 2; ++q) {   // Wh: 1024 slots of 16B
            int sid = q * 512 + tid;
            int o = sid >> 3, s = sid & 7;
            glds16(whB + (size_t)(bo0 + o) * 512 + c0 * 2 + ((s * 16) ^ ((o & 7) << 4)),
                   L + sid * 16);
        }
#pragma unroll
        for (int q = 0; q < 2; ++q) {   // Wl
            int sid = q * 512 + tid;
            int o = sid >> 3, s = sid & 7;
            glds16(wlB + (size_t)(bo0 + o) * 512 + c0 * 2 + ((s * 16) ^ ((o & 7) << 4)),
                   L + 16384 + sid * 16);
        }
#pragma unroll
        for (int q = 0; q < 2; ++q) {   // Xh
            int sid = q * 512 + tid;
            int n = sid >> 3, s = sid & 7;
            glds16(xhB + (size_t)(n0 + n) * 512 + c0 * 2 + ((s * 16) ^ ((n & 7) << 4)),
                   L + 32768 + sid * 16);
        }
#pragma unroll
        for (int q = 0; q < 2; ++q) {   // Xl
            int sid = q * 512 + tid;
            int n = sid >> 3, s = sid & 7;
            glds16(xlB + (size_t)(n0 + n) * 512 + c0 * 2 + ((s * 16) ^ ((n & 7) << 4)),
                   L + 49152 + sid * 16);
        }
        __syncthreads();
#pragma unroll
        for (int kk = 0; kk < 2; ++kk) {
            h8 awh[4], awl[4], bxh[2], bxl[2];
#pragma unroll
            for (int oi = 0; oi < 4; ++oi) {
                int o = wo * 64 + oi * 16 + l15;
                awh[oi] = *(const h8*)(L + o * 128 + ((kk * 64 + lg * 16) ^ ((o & 7) << 4)));
                awl[oi] = *(const h8*)(L + 16384 + o * 128 + ((kk * 64 + lg * 16) ^ ((o & 7) << 4)));
            }
#pragma unroll
            for (int nj = 0; nj < 2; ++nj) {
                int n = wn * 32 + nj * 16 + l15;
                bxh[nj] = *(const h8*)(L + 32768 + n * 128 + ((kk * 64 + lg * 16) ^ ((n & 7) << 4)));
                bxl[nj] = *(const h8*)(L + 49152 + n * 128 + ((kk * 64 + lg * 16) ^ ((n & 7) << 4)));
            }
#pragma unroll
            for (int oi = 0; oi < 4; ++oi)
#pragma unroll
                for (int nj = 0; nj < 2; ++nj) {
                    acc[oi][nj] = MFMA16(awh[oi], bxh[nj], acc[oi][nj]);
                    acc[oi][nj] = MFMA16(awh[oi], bxl[nj], acc[oi][nj]);
                    acc[oi][nj] = MFMA16(awl[oi], bxh[nj], acc[oi][nj]);
                }
        }
    }
    __syncthreads();
    if (!isV) {
        // epi tile [128 n][256B of o], XOR ((n&7)<<4)
#pragma unroll
        for (int oi = 0; oi < 4; ++oi)
#pragma unroll
            for (int nj = 0; nj < 2; ++nj) {
                int n = wn * 32 + nj * 16 + l15;
                int o = wo * 64 + oi * 16 + lg * 4;
                h4 r;
#pragma unroll
                for (int q = 0; q < 4; ++q) r[q] = (_Float16)acc[oi][nj][q];
                *(h4*)(L + n * 256 + ((o * 2) ^ ((n & 7) << 4))) = r;
            }
        __syncthreads();
        int n = tid >> 2, oq = (tid & 3) * 32;
        _Float16* dst = Yt + ((size_t)b * NN + n0 + n) * CC + bo0 + oq;
#pragma unroll
        for (int k = 0; k < 4; ++k)
            *(h8*)(dst + k * 8) = *(const h8*)(L + n * 256 + (((oq + k * 8) * 2) ^ ((n & 7) << 4)));
    } else {
        // epi tile [128 o][256B of n], XOR ((o&7)<<4)
#pragma unroll
        for (int oi = 0; oi < 4; ++oi)
#pragma unroll
            for (int nj = 0; nj < 2; ++nj) {
                int n = wn * 32 + nj * 16 + l15;
                int ob = wo * 64 + oi * 16 + lg * 4;
                f4 bb4 = *(const f4*)&bbS[ob];
#pragma unroll
                for (int r = 0; r < 4; ++r) {
                    int o = ob + r;
                    *(_Float16*)(L + o * 256 + ((n * 2) ^ ((o & 7) << 4))) =
                        (_Float16)(acc[oi][nj][r] + bb4[r]);
                }
            }
        __syncthreads();
        int o = tid >> 2, nq = (tid & 3) * 32;
        _Float16* dst = V + ((size_t)b * CC + bo0 - 256 + o) * NN + n0 + nq;
#pragma unroll
        for (int k = 0; k < 4; ++k)
            *(h8*)(dst + k * 8) = *(const h8*)(L + o * 256 + (((nq + k * 8) * 2) ^ ((o & 7) << 4)));
    }
}

// ---------------- K2: rsum via symmetric triangular 128x128 tiles, glds16 staging (verbatim r5).
__global__ __launch_bounds__(512, 4)
void rowsum_kernel(const _Float16* __restrict__ Yt, float* __restrict__ Rsum)
{
    __shared__ char As[16384];
    __shared__ char Bs[16384];
    __shared__ float rowred[128][2];
    __shared__ float colred[128][4];
    const int tid = threadIdx.x, lane = tid & 63, wid = tid >> 6;
    const int l15 = lane & 15, lg = lane >> 4;
    const int wn = wid >> 1, wm = wid & 1;
    int idx = blockIdx.x, I = 0;
    while (idx >= 16 - I) { idx -= 16 - I; ++I; }
    const int J = I + idx;
    const int b = blockIdx.y;
    const int nI0 = I * 128, nJ0 = J * 128;
    const char* Yb = (const char*)(Yt + (size_t)b * NN * CC);

    f4 eacc[2][4];
#pragma unroll
    for (int i = 0; i < 2; ++i)
#pragma unroll
        for (int j = 0; j < 4; ++j) eacc[i][j] = (f4){0.f, 0.f, 0.f, 0.f};

    for (int c0 = 0; c0 < CC; c0 += 64) {
        __syncthreads();
#pragma unroll
        for (int q = 0; q < 2; ++q) {
            int sid = q * 512 + tid;
            int n = sid >> 3, s = sid & 7;
            glds16(Yb + (size_t)(nI0 + n) * 512 + c0 * 2 + ((s * 16) ^ ((n & 7) << 4)),
                   As + sid * 16);
        }
#pragma unroll
        for (int q = 0; q < 2; ++q) {
            int sid = q * 512 + tid;
            int m = sid >> 3, s = sid & 7;
            glds16(Yb + (size_t)(nJ0 + m) * 512 + c0 * 2 + ((s * 16) ^ ((m & 7) << 4)),
                   Bs + sid * 16);
        }
        __syncthreads();
#pragma unroll
        for (int kk = 0; kk < 2; ++kk) {
            h8 a[2], bmf[4];
#pragma unroll
            for (int nt = 0; nt < 2; ++nt) {
                int n = wn * 32 + nt * 16 + l15;
                a[nt] = *(const h8*)(As + n * 128 + ((kk * 64 + lg * 16) ^ ((n & 7) << 4)));
            }
#pragma unroll
            for (int mt = 0; mt < 4; ++mt) {
                int m = wm * 64 + mt * 16 + l15;
                bmf[mt] = *(const h8*)(Bs + m * 128 + ((kk * 64 + lg * 16) ^ ((m & 7) << 4)));
            }
#pragma unroll
            for (int nt = 0; nt < 2; ++nt)
#pragma unroll
                for (int mt = 0; mt < 4; ++mt)
                    eacc[nt][mt] = MFMA16(a[nt], bmf[mt], eacc[nt][mt]);
        }
    }
    float rowp[2][4];
    float colp[4] = {0.f, 0.f, 0.f, 0.f};
#pragma unroll
    for (int nt = 0; nt < 2; ++nt)
#pragma unroll
        for (int r = 0; r < 4; ++r) rowp[nt][r] = 0.f;
#pragma unroll
    for (int nt = 0; nt < 2; ++nt)
#pragma unroll
        for (int mt = 0; mt < 4; ++mt)
#pragma unroll
            for (int r = 0; r < 4; ++r) {
                float p = __builtin_amdgcn_exp2f(eacc[nt][mt][r] - WSHIFT);
                rowp[nt][r] += p;
                colp[mt] += p;
            }
#pragma unroll
    for (int nt = 0; nt < 2; ++nt)
#pragma unroll
        for (int r = 0; r < 4; ++r) {
            float v = rowp[nt][r];
            v += __shfl_xor(v, 1); v += __shfl_xor(v, 2);
            v += __shfl_xor(v, 4); v += __shfl_xor(v, 8);
            if (l15 == 0) rowred[wn * 32 + nt * 16 + lg * 4 + r][wm] = v;
        }
#pragma unroll
    for (int mt = 0; mt < 4; ++mt) {
        float v = colp[mt];
        v += __shfl_xor(v, 16); v += __shfl_xor(v, 32);
        if (lg == 0) colred[wm * 64 + mt * 16 + l15][wn] = v;
    }
    __syncthreads();
    if (tid < 128)
        atomicAdd(&Rsum[(size_t)b * NN + nI0 + tid], rowred[tid][0] + rowred[tid][1]);
    if (I != J && tid >= 128 && tid < 256) {
        int m = tid - 128;
        atomicAdd(&Rsum[(size_t)b * NN + nJ0 + m],
                  colred[m][0] + colred[m][1] + colred[m][2] + colred[m][3]);
    }
}

// ---------------- K3: fused out2, 2 blocks/CU. Block owns (batch, 64-m-tile); n-steps of 256:
// e = yn.ym^T (glds, 4 c-chunks) -> w = exp2(e'-128)*rinv -> fp16 wT (32KB) -> PV (A=wT, B=v).
// grid 512 = 2 blocks/CU, XCD-pinned (2 batches/XCD). colsum in registers.
__global__ __launch_bounds__(512, 4)
void out2_kernel(const _Float16* __restrict__ Yt, const _Float16* __restrict__ V,
                 const float* __restrict__ Rsum, float* __restrict__ Out)
{
    __shared__ char stage[40960];   // e: yn[256][128B]@0, ym[64][128B]@32768 ; PV: v[256][128B]@0
    __shared__ char wT[32768];      // [64 m][512B], byte-in-row ^ ((m&7)<<4)
    __shared__ float rinvS[256];
    __shared__ float colred[64][4];
    __shared__ float colS[64];

    const int tid = threadIdx.x, lane = tid & 63, wid = tid >> 6;
    const int l15 = lane & 15, lg = lane >> 4;
    const int wn = wid >> 1, wm = wid & 1;   // e: wave 64n x 32m ; PV: wave 64c x 32m
    const int id = blockIdx.x;
    const int xcd = id & 7, j = id >> 3;     // j in [0,64)
    const int b = xcd * 2 + (j >> 5);        // 2 batches per XCD (L2 locality)
    const int gm0 = (j & 31) * 64;
    const char* Yb = (const char*)(Yt + (size_t)b * NN * CC);
    const char* Vb = (const char*)(V + (size_t)b * CC * NN);

    f4 oacc[2][4];   // [mt][ct]: lg*4+r <-> m (A=wT row), l15 <-> c (B=v row)
#pragma unroll
    for (int i = 0; i < 2; ++i)
#pragma unroll
        for (int jj = 0; jj < 4; ++jj) oacc[i][jj] = (f4){0.f, 0.f, 0.f, 0.f};
    float colp[2] = {0.f, 0.f};

    for (int gn0 = 0; gn0 < NN; gn0 += 256) {
        // ---- e-phase: e[256n][64m]
        f4 eacc[4][2];
#pragma unroll
        for (int i = 0; i < 4; ++i)
#pragma unroll
            for (int jj = 0; jj < 2; ++jj) eacc[i][jj] = (f4){0.f, 0.f, 0.f, 0.f};

        for (int c0 = 0; c0 < CC; c0 += 64) {
            __syncthreads();   // prev readers of stage done
            if (c0 == 0 && tid < 256)
                rinvS[tid] = 1.0f / Rsum[(size_t)b * NN + gn0 + tid];
#pragma unroll
            for (int q = 0; q < 4; ++q) {   // yn: 2048 slots of 16B
                int sid = q * 512 + tid;
                int n = sid >> 3, s = sid & 7;
                glds16(Yb + (size_t)(gn0 + n) * 512 + c0 * 2 + ((s * 16) ^ ((n & 7) << 4)),
                       stage + sid * 16);
            }
            {                                // ym: 512 slots
                int m = tid >> 3, s = tid & 7;
                glds16(Yb + (size_t)(gm0 + m) * 512 + c0 * 2 + ((s * 16) ^ ((m & 7) << 4)),
                       stage + 32768 + tid * 16);
            }
            __syncthreads();
#pragma unroll
            for (int kk = 0; kk < 2; ++kk) {
                h8 a[4], bmf[2];
#pragma unroll
                for (int nt = 0; nt < 4; ++nt) {
                    int n = wn * 64 + nt * 16 + l15;
                    a[nt] = *(const h8*)(stage + n * 128 + ((kk * 64 + lg * 16) ^ ((n & 7) << 4)));
                }
#pragma unroll
                for (int mt = 0; mt < 2; ++mt) {
                    int m = wm * 32 + mt * 16 + l15;
                    bmf[mt] = *(const h8*)(stage + 32768 + m * 128 + ((kk * 64 + lg * 16) ^ ((m & 7) << 4)));
                }
#pragma unroll
                for (int nt = 0; nt < 4; ++nt)
#pragma unroll
                    for (int mt = 0; mt < 2; ++mt)
                        eacc[nt][mt] = MFMA16(a[nt], bmf[mt], eacc[nt][mt]);
            }
        }

        // ---- w-phase: w[n][m] = exp2(e'-WSHIFT)*rinv[n] -> wT[m][n] fp16 in LDS
#pragma unroll
        for (int nt = 0; nt < 4; ++nt)
#pragma unroll
            for (int mt = 0; mt < 2; ++mt) {
                const int nl = wn * 64 + nt * 16 + lg * 4;
                const int m = wm * 32 + mt * 16 + l15;
                f4 e = eacc[nt][mt];
                f4 rv = *(const f4*)&rinvS[nl];
                float w0 = __builtin_amdgcn_exp2f(e[0] - WSHIFT) * rv[0];
                float w1 = __builtin_amdgcn_exp2f(e[1] - WSHIFT) * rv[1];
                float w2 = __builtin_amdgcn_exp2f(e[2] - WSHIFT) * rv[2];
                float w3 = __builtin_amdgcn_exp2f(e[3] - WSHIFT) * rv[3];
                colp[mt] += w0 + w1 + w2 + w3;
                h4 hw;
                hw[0] = (_Float16)w0; hw[1] = (_Float16)w1;
                hw[2] = (_Float16)w2; hw[3] = (_Float16)w3;
                *(h4*)(wT + m * 512 + ((nl * 2) ^ ((m & 7) << 4))) = hw;
            }
        __syncthreads();   // wT ready; all waves past e-phase (stage free)

        // ---- PV: out[256c][64m] += v . wT over this step's 256 n, 4 chunks of 64
        for (int kc = 0; kc < 4; ++kc) {
            if (kc) __syncthreads();
#pragma unroll
            for (int q = 0; q < 4; ++q) {   // v: 2048 slots
                int sid = q * 512 + tid;
                int c = sid >> 3, s = sid & 7;
                glds16(Vb + (size_t)c * (NN * 2) + (gn0 + kc * 64) * 2 + ((s * 16) ^ ((c & 7) << 4)),
                       stage + sid * 16);
            }
            __syncthreads();
#pragma unroll
            for (int kk = 0; kk < 2; ++kk) {
                h8 aw[2], bvf[4];
#pragma unroll
                for (int mt = 0; mt < 2; ++mt) {
                    int m = wm * 32 + mt * 16 + l15;
                    aw[mt] = *(const h8*)(wT + m * 512 + ((kc * 128 + kk * 64 + lg * 16) ^ ((m & 7) << 4)));
                }
#pragma unroll
                for (int ct = 0; ct < 4; ++ct) {
                    int c = wn * 64 + ct * 16 + l15;
                    bvf[ct] = *(const h8*)(stage + c * 128 + ((kk * 64 + lg * 16) ^ ((c & 7) << 4)));
                }
#pragma unroll
                for (int mt = 0; mt < 2; ++mt)
#pragma unroll
                    for (int ct = 0; ct < 4; ++ct)
                        oacc[mt][ct] = MFMA16(aw[mt], bvf[ct], oacc[mt][ct]);
            }
        }
    }

    // ---- colsum reduce; scale; store
#pragma unroll
    for (int mt = 0; mt < 2; ++mt) {
        float v = colp[mt];
        v += __shfl_xor(v, 16); v += __shfl_xor(v, 32);
        if (lg == 0) colred[wm * 32 + mt * 16 + l15][wn] = v;
    }
    __syncthreads();
    if (tid < 64) {
        float s = colred[tid][0] + colred[tid][1] + colred[tid][2] + colred[tid][3];
        colS[tid] = 1.0f / ((1e-9f + s) * 16.0f);   // 16 = sqrt(C)
    }
    __syncthreads();
#pragma unroll
    for (int mt = 0; mt < 2; ++mt) {
        const int m0 = wm * 32 + mt * 16 + lg * 4;
        f4 sc = *(const f4*)&colS[m0];
#pragma unroll
        for (int ct = 0; ct < 4; ++ct) {
            const int c = wn * 64 + ct * 16 + l15;
            f4 r;
#pragma unroll
            for (int q = 0; q < 4; ++q) r[q] = oacc[mt][ct][q] * sc[q];
            *(f4*)(Out + ((size_t)b * CC + c) * NN + gm0 + m0) = r;
        }
    }
}

extern "C" void kernel_launch(void* const* d_in, const int* in_sizes, int n_in,
                              void* d_out, int out_size, void* d_ws, size_t ws_size,
                              hipStream_t stream)
{
    const float* x   = (const float*)d_in[0];
    const float* Wqk = (const float*)d_in[1];
    const float* Wv  = (const float*)d_in[2];
    const float* bv  = (const float*)d_in[3];
    float* out = (float*)d_out;

    const size_t NE = (size_t)BB * NN * CC;
    _Float16* xh = (_Float16*)d_ws;
    _Float16* xl = xh + NE;
    _Float16* wh = xl + NE;
    _Float16* wl = wh + (size_t)512 * CC;
    _Float16* yt = wl + (size_t)512 * CC;
    _Float16* v  = yt + NE;
    float* rsum  = (float*)(v + NE);

    hipMemsetAsync(rsum, 0, (size_t)BB * NN * sizeof(float), stream);

    convw_kernel<<<dim3(512), dim3(64), 0, stream>>>(Wqk, Wv, wh, wl);
    transx_kernel<<<dim3(NN / 64, CC / 64, BB), dim3(256), 0, stream>>>(x, xh, xl);
    proj_kernel<<<dim3(NN / 128, 4, BB), dim3(512), 0, stream>>>(xh, xl, wh, wl, bv, yt, v);
    rowsum_kernel<<<dim3(136, BB), dim3(512), 0, stream>>>(yt, rsum);
    out2_kernel<<<dim3(512), dim3(512), 0, stream>>>(yt, v, rsum, out);
}